// Round 1
// baseline (3758.697 us; speedup 1.0000x reference)
//
#include <hip/hip_runtime.h>
#include <cmath>

// ---------------------------------------------------------------- helpers
__device__ __forceinline__ float silu_f(float x) {
    return x / (1.0f + __expf(-x));
}

// ---------------------------------------------------------------- rbf (E,6)
__global__ __launch_bounds__(256) void rbf_kernel(const float* __restrict__ d,
                                                  float* __restrict__ rbf, int E) {
    int e = blockIdx.x * 256 + threadIdx.x;
    if (e >= E) return;
    float x = d[e] * 0.2f;               // d / CUTOFF
    float env = 0.0f;
    if (x < 1.0f) {
        float x2 = x * x;
        float x5 = x2 * x2 * x;
        env = 1.0f / x + x5 * (-28.0f + x * (48.0f - 21.0f * x));
    }
    const float SQ = 0.63245553f;        // sqrt(2/5)
    float px = 3.14159265358979f * x;
    #pragma unroll
    for (int n = 1; n <= 6; n++) {
        rbf[e * 6 + n - 1] = SQ * env * sinf(px * (float)n);
    }
}

// ------------------------------------------- embedding precompute (1 block)
// HWj[s][c] = sum_k se[s][k] * edw[k][c]          (k in 0..63)
// HWi[s][c] = sum_k se[s][k] * edw[64+k][c]
// W3[r][c]  = sum_k erw[r][k] * edw[128+k][c]
// b3[c]     = sum_k erb[k]   * edw[128+k][c]
__global__ __launch_bounds__(128) void embed_pre_kernel(
    const float* __restrict__ se, const float* __restrict__ erw,
    const float* __restrict__ erb, const float* __restrict__ edw,
    float* __restrict__ HWj, float* __restrict__ HWi,
    float* __restrict__ W3, float* __restrict__ b3) {
    int c = threadIdx.x;
    for (int s = 0; s < 16; s++) {
        float aj = 0.f, ai = 0.f;
        for (int k = 0; k < 64; k++) {
            float h = se[s * 64 + k];
            aj += h * edw[k * 128 + c];
            ai += h * edw[(64 + k) * 128 + c];
        }
        HWj[s * 128 + c] = aj;
        HWi[s * 128 + c] = ai;
    }
    for (int r = 0; r < 6; r++) {
        float a = 0.f;
        for (int k = 0; k < 128; k++) a += erw[r * 128 + k] * edw[(128 + k) * 128 + c];
        W3[r * 128 + c] = a;
    }
    float a = 0.f;
    for (int k = 0; k < 128; k++) a += erb[k] * edw[(128 + k) * 128 + c];
    b3[c] = a;
}

// ---------------------------------------------------------------- m (E,128)
__global__ __launch_bounds__(256) void embed_kernel(
    const float* __restrict__ rbf, const int* __restrict__ species,
    const int* __restrict__ idx_i, const int* __restrict__ idx_j,
    const float* __restrict__ HWj, const float* __restrict__ HWi,
    const float* __restrict__ W3, const float* __restrict__ b3,
    const float* __restrict__ edb, float* __restrict__ m) {
    int gid = blockIdx.x * 256 + threadIdx.x;
    int e = gid >> 7, c = gid & 127;
    int sj = species[idx_j[e]];
    int si = species[idx_i[e]];
    float v = HWj[sj * 128 + c] + HWi[si * 128 + c] + b3[c] + edb[c];
    #pragma unroll
    for (int k = 0; k < 6; k++) v += rbf[e * 6 + k] * W3[k * 128 + c];
    m[gid] = silu_f(v);
}

// ------------------------------------------------ generic fp32 dense GEMM
// Y = [RES? resid + ] [ACT? silu] ( X(MxK) @ W(KxN) [BIAS? + bias] )
// BM=128 BN=64 BK=16, 256 threads, 8x4 per-thread tile.
template <int ACT, int BIAS, int RES>
__global__ __launch_bounds__(256) void dense_gemm(
    const float* __restrict__ X, const float* __restrict__ W,
    const float* __restrict__ bias, const float* __restrict__ resid,
    float* __restrict__ Y, int M, int K, int N) {
    __shared__ float Xs[16][128];
    __shared__ float Ws[16][64];
    int tid = threadIdx.x;
    int bm = blockIdx.x * 128, bn = blockIdx.y * 64;
    int tr = (tid >> 4) << 3;   // 0..120
    int tc = (tid & 15) << 2;   // 0..60
    float acc[8][4];
    #pragma unroll
    for (int i = 0; i < 8; i++)
        #pragma unroll
        for (int j = 0; j < 4; j++) acc[i][j] = 0.f;

    for (int k0 = 0; k0 < K; k0 += 16) {
        #pragma unroll
        for (int p = 0; p < 8; p++) {
            int idx = tid + p * 256;
            int mm = idx >> 4, kk = idx & 15;
            Xs[kk][mm] = X[(size_t)(bm + mm) * K + k0 + kk];
        }
        #pragma unroll
        for (int p = 0; p < 4; p++) {
            int idx = tid + p * 256;
            int kk = idx >> 6, nn = idx & 63;
            Ws[kk][nn] = W[(size_t)(k0 + kk) * N + bn + nn];
        }
        __syncthreads();
        #pragma unroll
        for (int kk = 0; kk < 16; kk++) {
            float a[8], b[4];
            #pragma unroll
            for (int i = 0; i < 8; i++) a[i] = Xs[kk][tr + i];
            #pragma unroll
            for (int j = 0; j < 4; j++) b[j] = Ws[kk][tc + j];
            #pragma unroll
            for (int i = 0; i < 8; i++)
                #pragma unroll
                for (int j = 0; j < 4; j++) acc[i][j] += a[i] * b[j];
        }
        __syncthreads();
    }
    #pragma unroll
    for (int i = 0; i < 8; i++) {
        size_t r = bm + tr + i;
        #pragma unroll
        for (int j = 0; j < 4; j++) {
            int c = bn + tc + j;
            float v = acc[i][j];
            if (BIAS) v += bias[c];
            if (ACT) v = silu_f(v);
            if (RES) v += resid[r * N + c];
            Y[r * N + c] = v;
        }
    }
}

// ------------------------------------- x_kj *= (rbf @ rbf1) @ rbf2  (E,128)
__global__ __launch_bounds__(256) void mulg_kernel(
    const float* __restrict__ rbf, const float* __restrict__ rbf1,
    const float* __restrict__ rbf2, float* __restrict__ xkj) {
    int gid = blockIdx.x * 256 + threadIdx.x;
    int e = gid >> 7, c = gid & 127;
    float r[6];
    #pragma unroll
    for (int k = 0; k < 6; k++) r[k] = rbf[e * 6 + k];
    float s = 0.f;
    #pragma unroll
    for (int p = 0; p < 8; p++) {
        float g = 0.f;
        #pragma unroll
        for (int k = 0; k < 6; k++) g += r[k] * rbf1[k * 8 + p];
        s += g * rbf2[p * 128 + c];
    }
    xkj[gid] *= s;
}

// ------------------------------- output block scatter: atom += seg(rbfw * m)
__global__ __launch_bounds__(256) void outseg_kernel(
    const float* __restrict__ rbf, const float* __restrict__ orw,
    const float* __restrict__ m, const int* __restrict__ idx_i,
    float* __restrict__ atom) {
    int gid = blockIdx.x * 256 + threadIdx.x;
    int e = gid >> 7, c = gid & 127;
    float s = 0.f;
    #pragma unroll
    for (int k = 0; k < 6; k++) s += rbf[e * 6 + k] * orw[k * 128 + c];
    atomicAdd(&atom[(size_t)idx_i[e] * 128 + c], s * m[gid]);
}

// ---------------------------------------------- final: out[a] += atom . wf
__global__ __launch_bounds__(64) void final_kernel(
    const float* __restrict__ atom, const float* __restrict__ wf,
    float* __restrict__ out) {
    int a = blockIdx.x, l = threadIdx.x;
    float s = 0.f;
    #pragma unroll
    for (int q = 0; q < 4; q++) s += atom[(size_t)a * 256 + q * 64 + l] * wf[q * 64 + l];
    #pragma unroll
    for (int off = 32; off; off >>= 1) s += __shfl_down(s, off, 64);
    if (l == 0) out[a] += s;
}

// ----------------------------------------------------------- triplet kernel
// For each triplet t: sbf(42) -> t8 = sbf@sbf1 -> v64 = t8@sbf2,
// y = xdown[ekj[t]] * v64, atomicAdd into seg[rji[t]].
__global__ __launch_bounds__(256) void triplet_kernel(
    const float* __restrict__ dist, const float* __restrict__ angles,
    const int* __restrict__ ekj, const int* __restrict__ rji,
    const float* __restrict__ xdown, const float* __restrict__ sbf1,
    const float* __restrict__ sbf2, float* __restrict__ seg) {
    __shared__ float t8s[256][8];
    __shared__ float s1[336];
    __shared__ float s2[512];
    __shared__ int eks[256];
    __shared__ int rjs[256];
    int tid = threadIdx.x;
    for (int i = tid; i < 336; i += 256) s1[i] = sbf1[i];
    for (int i = tid; i < 512; i += 256) s2[i] = sbf2[i];

    int t = blockIdx.x * 256 + tid;
    int e = ekj[t];
    eks[tid] = e;
    rjs[tid] = rji[t];

    float x = fmaxf(dist[e] * 0.2f, 1e-6f);
    float env = 0.f;
    if (x < 1.0f) {
        float x2 = x * x;
        float x5 = x2 * x2 * x;
        env = 1.0f / x + x5 * (-28.0f + x * (48.0f - 21.0f * x));
    }
    float ct = cosf(angles[t]);
    float Pl[7];
    Pl[0] = 1.f;
    Pl[1] = ct;
    #pragma unroll
    for (int l = 2; l < 7; l++)
        Pl[l] = ((2.f * l - 1.f) * ct * Pl[l - 1] - (l - 1.f) * Pl[l - 2]) / (float)l;
    const float sphc[7] = {0.28209479f, 0.48860251f, 0.63078313f, 0.74635267f,
                           0.84628438f, 0.93560257f, 1.01710723f};
    const float BZ[7][6] = {
        {3.141593f, 6.283185f, 9.424778f, 12.566371f, 15.707963f, 18.849556f},
        {4.493409f, 7.725252f, 10.904122f, 14.066194f, 17.220755f, 20.371303f},
        {5.763459f, 9.095011f, 12.322941f, 15.514603f, 18.689036f, 21.853874f},
        {6.987932f, 10.417119f, 13.698023f, 16.923621f, 20.121806f, 23.304247f},
        {8.182561f, 11.704907f, 15.039665f, 18.301256f, 21.525418f, 24.727566f},
        {9.355812f, 12.966530f, 16.354710f, 19.653152f, 22.904551f, 26.126750f},
        {10.512835f, 14.207392f, 17.647975f, 20.983463f, 24.262768f, 27.507868f}};
    float t8[8] = {0, 0, 0, 0, 0, 0, 0, 0};
    #pragma unroll
    for (int l = 0; l < 7; l++) {
        float coef = env * sphc[l] * Pl[l];
        #pragma unroll
        for (int n = 0; n < 6; n++) {
            float a = BZ[l][n] * x;
            float sa, ca;
            sincosf(a, &sa, &ca);
            float inv = 1.0f / a;
            float j;
            if (l == 0) {
                j = sa * inv;
            } else {
                float jm2 = sa * inv;
                float jm1 = (sa * inv - ca) * inv;   // sin/a^2 - cos/a
                #pragma unroll
                for (int ll = 2; ll <= l; ll++) {
                    float jn = (2.f * ll - 1.f) * inv * jm1 - jm2;
                    jm2 = jm1;
                    jm1 = jn;
                }
                j = jm1;
            }
            float s = coef * j;
            const float* s1r = &s1[(l * 6 + n) * 8];
            #pragma unroll
            for (int p = 0; p < 8; p++) t8[p] += s * s1r[p];
        }
    }
    #pragma unroll
    for (int p = 0; p < 8; p++) t8s[tid][p] = t8[p];
    __syncthreads();

    int w = tid >> 6, lane = tid & 63;
    float w2[8];
    #pragma unroll
    for (int p = 0; p < 8; p++) w2[p] = s2[p * 64 + lane];
    for (int jj = 0; jj < 64; jj++) {
        int tt = (w << 6) + jj;
        const float4* row = (const float4*)(&t8s[tt][0]);
        float4 q0 = row[0], q1 = row[1];
        float v = q0.x * w2[0] + q0.y * w2[1] + q0.z * w2[2] + q0.w * w2[3] +
                  q1.x * w2[4] + q1.y * w2[5] + q1.z * w2[6] + q1.w * w2[7];
        float y = xdown[(size_t)eks[tt] * 64 + lane] * v;
        atomicAdd(&seg[(size_t)rjs[tt] * 64 + lane], y);
    }
}

// ---------------------------------------------------------------- launcher
extern "C" void kernel_launch(void* const* d_in, const int* in_sizes, int n_in,
                              void* d_out, int out_size, void* d_ws, size_t ws_size,
                              hipStream_t stream) {
    const float* distances   = (const float*)d_in[0];
    const float* angles      = (const float*)d_in[1];
    const float* species_emb = (const float*)d_in[2];
    const float* emb_rbf_w   = (const float*)d_in[3];
    const float* emb_rbf_b   = (const float*)d_in[4];
    const float* emb_dense_w = (const float*)d_in[5];
    const float* emb_dense_b = (const float*)d_in[6];
    const float* out_rbf_w   = (const float*)d_in[7];
    const float* out_up_w    = (const float*)d_in[8];
    const float* out_dense_w = (const float*)d_in[9];
    const float* out_dense_b = (const float*)d_in[10];
    const float* out_final_w = (const float*)d_in[11];
    const float* int_ji_w    = (const float*)d_in[12];
    const float* int_ji_b    = (const float*)d_in[13];
    const float* int_kj_w    = (const float*)d_in[14];
    const float* int_kj_b    = (const float*)d_in[15];
    const float* int_rbf1_w  = (const float*)d_in[16];
    const float* int_rbf2_w  = (const float*)d_in[17];
    const float* int_down_w  = (const float*)d_in[18];
    const float* int_sbf1_w  = (const float*)d_in[19];
    const float* int_sbf2_w  = (const float*)d_in[20];
    const float* int_up_w    = (const float*)d_in[21];
    const float* int_res1_w  = (const float*)d_in[22];
    const float* int_res1_b  = (const float*)d_in[23];
    const float* int_skip_w  = (const float*)d_in[24];
    const float* int_skip_b  = (const float*)d_in[25];
    const float* int_res2_w  = (const float*)d_in[26];
    const float* int_res2_b  = (const float*)d_in[27];
    const int*   species     = (const int*)d_in[28];
    const int*   idx_i       = (const int*)d_in[29];
    const int*   idx_j       = (const int*)d_in[30];
    const int*   reduce_ji   = (const int*)d_in[31];
    const int*   expand_kj   = (const int*)d_in[32];
    // d_in[33]/[34]: edge_mask / triplet_mask — all true in this problem.

    const int E = in_sizes[0];       // 65536
    const int T = in_sizes[1];       // 524288
    const int NA = in_sizes[28];     // 4096

    float* ws = (float*)d_ws;
    size_t off = 0;
    float* rbf = ws + off;   off += (size_t)E * 6;
    float* m   = ws + off;   off += (size_t)E * 128;
    float* A   = ws + off;   off += (size_t)E * 128;
    float* B   = ws + off;   off += (size_t)E * 128;
    float* C   = ws + off;   off += (size_t)E * 128;
    float* D   = ws + off;   off += (size_t)E * 64;
    float* HWj = ws + off;   off += 16 * 128;
    float* HWi = ws + off;   off += 16 * 128;
    float* W3  = ws + off;   off += 6 * 128;
    float* b3  = ws + off;   off += 128;
    float* atom1 = ws + off; off += (size_t)NA * 128;
    float* atom2 = ws + off; off += (size_t)NA * 256;
    float* atom3 = ws + off; off += (size_t)NA * 256;
    float* seg = B;  // reuse B (dead at that point) as (E,64) segment buffer

    float* out = (float*)d_out;
    hipMemsetAsync(out, 0, (size_t)out_size * sizeof(float), stream);

    rbf_kernel<<<E / 256, 256, 0, stream>>>(distances, rbf, E);
    embed_pre_kernel<<<1, 128, 0, stream>>>(species_emb, emb_rbf_w, emb_rbf_b,
                                            emb_dense_w, HWj, HWi, W3, b3);
    embed_kernel<<<E * 128 / 256, 256, 0, stream>>>(rbf, species, idx_i, idx_j,
                                                    HWj, HWi, W3, b3, emb_dense_b, m);

    auto outblock = [&](int i, const float* msg) {
        hipMemsetAsync(atom1, 0, (size_t)NA * 128 * sizeof(float), stream);
        outseg_kernel<<<E * 128 / 256, 256, 0, stream>>>(
            rbf, out_rbf_w + (size_t)i * 6 * 128, msg, idx_i, atom1);
        dense_gemm<0, 0, 0><<<dim3(NA / 128, 4), 256, 0, stream>>>(
            atom1, out_up_w + (size_t)i * 128 * 256, nullptr, nullptr, atom2, NA, 128, 256);
        dense_gemm<1, 1, 0><<<dim3(NA / 128, 4), 256, 0, stream>>>(
            atom2, out_dense_w + ((size_t)i * 3 + 0) * 256 * 256,
            out_dense_b + ((size_t)i * 3 + 0) * 256, nullptr, atom3, NA, 256, 256);
        dense_gemm<1, 1, 0><<<dim3(NA / 128, 4), 256, 0, stream>>>(
            atom3, out_dense_w + ((size_t)i * 3 + 1) * 256 * 256,
            out_dense_b + ((size_t)i * 3 + 1) * 256, nullptr, atom2, NA, 256, 256);
        dense_gemm<1, 1, 0><<<dim3(NA / 128, 4), 256, 0, stream>>>(
            atom2, out_dense_w + ((size_t)i * 3 + 2) * 256 * 256,
            out_dense_b + ((size_t)i * 3 + 2) * 256, nullptr, atom3, NA, 256, 256);
        final_kernel<<<NA, 64, 0, stream>>>(atom3, out_final_w + (size_t)i * 256, out);
    };

    outblock(0, m);

    for (int i = 0; i < 4; i++) {
        size_t w128 = (size_t)i * 128 * 128;
        // x_ji = silu(m @ ji + b)
        dense_gemm<1, 1, 0><<<dim3(E / 128, 2), 256, 0, stream>>>(
            m, int_ji_w + w128, int_ji_b + (size_t)i * 128, nullptr, A, E, 128, 128);
        // x_kj = silu(m @ kj + b)
        dense_gemm<1, 1, 0><<<dim3(E / 128, 2), 256, 0, stream>>>(
            m, int_kj_w + w128, int_kj_b + (size_t)i * 128, nullptr, B, E, 128, 128);
        // x_kj *= (rbf @ rbf1) @ rbf2
        mulg_kernel<<<E * 128 / 256, 256, 0, stream>>>(
            rbf, int_rbf1_w + (size_t)i * 48, int_rbf2_w + (size_t)i * 8 * 128, B);
        // xdown = silu(x_kj @ down)   (no bias)
        dense_gemm<1, 0, 0><<<dim3(E / 128, 1), 256, 0, stream>>>(
            B, int_down_w + (size_t)i * 128 * 64, nullptr, nullptr, D, E, 128, 64);
        // triplet scatter into seg (reuses B)
        hipMemsetAsync(seg, 0, (size_t)E * 64 * sizeof(float), stream);
        triplet_kernel<<<T / 256, 256, 0, stream>>>(
            distances, angles, expand_kj, reduce_ji, D,
            int_sbf1_w + (size_t)i * 42 * 8, int_sbf2_w + (size_t)i * 8 * 64, seg);
        // hm = x_ji + silu(seg @ up)   (no bias)
        dense_gemm<1, 0, 1><<<dim3(E / 128, 2), 256, 0, stream>>>(
            seg, int_up_w + (size_t)i * 64 * 128, nullptr, A, C, E, 64, 128);
        // res-before: t = silu(hm @ w0 + b0); hm = hm + silu(t @ w1 + b1)
        dense_gemm<1, 1, 0><<<dim3(E / 128, 2), 256, 0, stream>>>(
            C, int_res1_w + ((size_t)i * 2 + 0) * 16384,
            int_res1_b + ((size_t)i * 2 + 0) * 128, nullptr, A, E, 128, 128);
        dense_gemm<1, 1, 1><<<dim3(E / 128, 2), 256, 0, stream>>>(
            A, int_res1_w + ((size_t)i * 2 + 1) * 16384,
            int_res1_b + ((size_t)i * 2 + 1) * 128, C, B, E, 128, 128);
        // m = silu(hm @ skip + b) + m   (in-place resid on m)
        dense_gemm<1, 1, 1><<<dim3(E / 128, 2), 256, 0, stream>>>(
            B, int_skip_w + w128, int_skip_b + (size_t)i * 128, m, m, E, 128, 128);
        // res-after x2
        for (int r = 0; r < 2; r++) {
            dense_gemm<1, 1, 0><<<dim3(E / 128, 2), 256, 0, stream>>>(
                m, int_res2_w + (((size_t)i * 2 + r) * 2 + 0) * 16384,
                int_res2_b + (((size_t)i * 2 + r) * 2 + 0) * 128, nullptr, A, E, 128, 128);
            dense_gemm<1, 1, 1><<<dim3(E / 128, 2), 256, 0, stream>>>(
                A, int_res2_w + (((size_t)i * 2 + r) * 2 + 1) * 16384,
                int_res2_b + (((size_t)i * 2 + r) * 2 + 1) * 128, m, m, E, 128, 128);
        }
        outblock(i + 1, m);
    }
}

// Round 2
// 3169.911 us; speedup vs baseline: 1.1857x; 1.1857x over previous
//
#include <hip/hip_runtime.h>
#include <cmath>

typedef __attribute__((ext_vector_type(8))) short bfrag;   // 8 bf16 = 4 VGPRs
typedef __attribute__((ext_vector_type(4))) float f32x4;

// ---------------------------------------------------------------- helpers
__device__ __forceinline__ float silu_f(float x) {
    return x / (1.0f + __expf(-x));
}
__device__ __forceinline__ unsigned short f2bf(float f) {
    unsigned u = __float_as_uint(f);
    unsigned r = (u + 0x7fff + ((u >> 16) & 1)) >> 16;
    return (unsigned short)r;
}
__device__ __forceinline__ float bf2f(unsigned short h) {
    return __uint_as_float(((unsigned)h) << 16);
}

// ---------------------------------------------------------------- rbf (E,6)
__global__ __launch_bounds__(256) void rbf_kernel(const float* __restrict__ d,
                                                  float* __restrict__ rbf, int E) {
    int e = blockIdx.x * 256 + threadIdx.x;
    if (e >= E) return;
    float x = d[e] * 0.2f;               // d / CUTOFF
    float env = 0.0f;
    if (x < 1.0f) {
        float x2 = x * x;
        float x5 = x2 * x2 * x;
        env = 1.0f / x + x5 * (-28.0f + x * (48.0f - 21.0f * x));
    }
    const float SQ = 0.63245553f;        // sqrt(2/5)
    float px = 3.14159265358979f * x;
    #pragma unroll
    for (int n = 1; n <= 6; n++) {
        rbf[e * 6 + n - 1] = SQ * env * sinf(px * (float)n);
    }
}

// ------------------------------------------- embedding precompute (1 block)
__global__ __launch_bounds__(128) void embed_pre_kernel(
    const float* __restrict__ se, const float* __restrict__ erw,
    const float* __restrict__ erb, const float* __restrict__ edw,
    float* __restrict__ HWj, float* __restrict__ HWi,
    float* __restrict__ W3, float* __restrict__ b3) {
    int c = threadIdx.x;
    for (int s = 0; s < 16; s++) {
        float aj = 0.f, ai = 0.f;
        for (int k = 0; k < 64; k++) {
            float h = se[s * 64 + k];
            aj += h * edw[k * 128 + c];
            ai += h * edw[(64 + k) * 128 + c];
        }
        HWj[s * 128 + c] = aj;
        HWi[s * 128 + c] = ai;
    }
    for (int r = 0; r < 6; r++) {
        float a = 0.f;
        for (int k = 0; k < 128; k++) a += erw[r * 128 + k] * edw[(128 + k) * 128 + c];
        W3[r * 128 + c] = a;
    }
    float a = 0.f;
    for (int k = 0; k < 128; k++) a += erb[k] * edw[(128 + k) * 128 + c];
    b3[c] = a;
}

// ---------------------------------------------------------------- m (E,128)
__global__ __launch_bounds__(256) void embed_kernel(
    const float* __restrict__ rbf, const int* __restrict__ species,
    const int* __restrict__ idx_i, const int* __restrict__ idx_j,
    const float* __restrict__ HWj, const float* __restrict__ HWi,
    const float* __restrict__ W3, const float* __restrict__ b3,
    const float* __restrict__ edb, float* __restrict__ m) {
    int gid = blockIdx.x * 256 + threadIdx.x;
    int e = gid >> 7, c = gid & 127;
    int sj = species[idx_j[e]];
    int si = species[idx_i[e]];
    float v = HWj[sj * 128 + c] + HWi[si * 128 + c] + b3[c] + edb[c];
    #pragma unroll
    for (int k = 0; k < 6; k++) v += rbf[e * 6 + k] * W3[k * 128 + c];
    m[gid] = silu_f(v);
}

// -------------------------------------- weight transpose+split (batched)
// in:  W [B][K][N] fp32 ;  out: hi/lo [B][N][K] bf16 planes
__global__ __launch_bounds__(256) void wconv_kernel(
    const float* __restrict__ W, unsigned short* __restrict__ hi,
    unsigned short* __restrict__ lo, int K, int N) {
    __shared__ float t[32][33];
    int b = blockIdx.z;
    int n0 = blockIdx.x * 32, k0 = blockIdx.y * 32;
    const float* Wb = W + (size_t)b * K * N;
    int tid = threadIdx.x;
    int r = tid >> 3, cg = tid & 7;
    float4 v = *(const float4*)&Wb[(size_t)(k0 + r) * N + n0 + cg * 4];
    t[r][cg * 4 + 0] = v.x;
    t[r][cg * 4 + 1] = v.y;
    t[r][cg * 4 + 2] = v.z;
    t[r][cg * 4 + 3] = v.w;
    __syncthreads();
    int nl = tid >> 3, kg = tid & 7;
    short4 h4, l4;
    float f0 = t[kg * 4 + 0][nl], f1 = t[kg * 4 + 1][nl];
    float f2 = t[kg * 4 + 2][nl], f3 = t[kg * 4 + 3][nl];
    unsigned short h;
    h = f2bf(f0); h4.x = (short)h; l4.x = (short)f2bf(f0 - bf2f(h));
    h = f2bf(f1); h4.y = (short)h; l4.y = (short)f2bf(f1 - bf2f(h));
    h = f2bf(f2); h4.z = (short)h; l4.z = (short)f2bf(f2 - bf2f(h));
    h = f2bf(f3); h4.w = (short)h; l4.w = (short)f2bf(f3 - bf2f(h));
    size_t o = ((size_t)b * N + n0 + nl) * K + k0 + kg * 4;
    *(short4*)&hi[o] = h4;
    *(short4*)&lo[o] = l4;
}

// ---------------------------------------------- split-bf16 MFMA dense GEMM
// Y = [RES? resid + ] [ACT? silu] ( X(MxK) @ W(KxN) [BIAS? + bias] )
// W pre-converted to bf16 hi/lo planes in [N][K] layout.
// BM=128, BN template (64 or 128), threads = 4*BN, wave tile 64x32.
template <int BN, int ACT, int BIAS, int RES>
__global__ __launch_bounds__(BN * 4) void mfma_gemm(
    const float* __restrict__ X, const unsigned short* __restrict__ Whi,
    const unsigned short* __restrict__ Wlo,
    const float* __restrict__ bias, const float* __restrict__ resid,
    float* __restrict__ Y, int M, int K, int N) {
    constexpr int T = BN * 4;        // threads
    constexpr int WC = BN / 32;      // wave columns
    constexpr int AP = 1024 / T;     // float4 loads per thread for A tile
    __shared__ unsigned short Ah[128 * 40];
    __shared__ unsigned short Al[128 * 40];
    __shared__ unsigned short Bh[BN * 40];
    __shared__ unsigned short Bl[BN * 40];

    int tid = threadIdx.x;
    int bm = blockIdx.x * 128, bn = blockIdx.y * BN;
    int wid = tid >> 6, lane = tid & 63;
    int wr = wid / WC, wc = wid % WC;
    int r16 = lane & 15, kg = lane >> 4;

    f32x4 acc[4][2];
    #pragma unroll
    for (int s = 0; s < 4; s++)
        #pragma unroll
        for (int ns = 0; ns < 2; ns++) acc[s][ns] = (f32x4)0.f;

    int brow = tid >> 2, bkg = tid & 3;

    for (int k0 = 0; k0 < K; k0 += 32) {
        float4 av[AP];
        #pragma unroll
        for (int p = 0; p < AP; p++) {
            int idx = tid + p * T;
            int row = idx >> 3, cg = idx & 7;
            av[p] = *(const float4*)&X[(size_t)(bm + row) * K + k0 + cg * 4];
        }
        float4 bh = *(const float4*)&Whi[(size_t)(bn + brow) * K + k0 + bkg * 8];
        float4 bl = *(const float4*)&Wlo[(size_t)(bn + brow) * K + k0 + bkg * 8];
        __syncthreads();
        #pragma unroll
        for (int p = 0; p < AP; p++) {
            int idx = tid + p * T;
            int row = idx >> 3, cg = idx & 7;
            float fv[4] = {av[p].x, av[p].y, av[p].z, av[p].w};
            short4 h4, l4;
            unsigned short h;
            h = f2bf(fv[0]); h4.x = (short)h; l4.x = (short)f2bf(fv[0] - bf2f(h));
            h = f2bf(fv[1]); h4.y = (short)h; l4.y = (short)f2bf(fv[1] - bf2f(h));
            h = f2bf(fv[2]); h4.z = (short)h; l4.z = (short)f2bf(fv[2] - bf2f(h));
            h = f2bf(fv[3]); h4.w = (short)h; l4.w = (short)f2bf(fv[3] - bf2f(h));
            *(short4*)&Ah[row * 40 + cg * 4] = h4;
            *(short4*)&Al[row * 40 + cg * 4] = l4;
        }
        *(float4*)&Bh[brow * 40 + bkg * 8] = bh;
        *(float4*)&Bl[brow * 40 + bkg * 8] = bl;
        __syncthreads();

        bfrag bhf[2], blf[2];
        #pragma unroll
        for (int ns = 0; ns < 2; ns++) {
            int br = wc * 32 + ns * 16 + r16;
            bhf[ns] = *(const bfrag*)&Bh[br * 40 + kg * 8];
            blf[ns] = *(const bfrag*)&Bl[br * 40 + kg * 8];
        }
        #pragma unroll
        for (int s = 0; s < 4; s++) {
            int ar = wr * 64 + s * 16 + r16;
            bfrag ah = *(const bfrag*)&Ah[ar * 40 + kg * 8];
            bfrag al = *(const bfrag*)&Al[ar * 40 + kg * 8];
            #pragma unroll
            for (int ns = 0; ns < 2; ns++) {
                acc[s][ns] = __builtin_amdgcn_mfma_f32_16x16x32_bf16(ah, bhf[ns], acc[s][ns], 0, 0, 0);
                acc[s][ns] = __builtin_amdgcn_mfma_f32_16x16x32_bf16(ah, blf[ns], acc[s][ns], 0, 0, 0);
                acc[s][ns] = __builtin_amdgcn_mfma_f32_16x16x32_bf16(al, bhf[ns], acc[s][ns], 0, 0, 0);
            }
        }
    }

    #pragma unroll
    for (int s = 0; s < 4; s++) {
        int row0 = bm + wr * 64 + s * 16 + kg * 4;
        #pragma unroll
        for (int ns = 0; ns < 2; ns++) {
            int col = bn + wc * 32 + ns * 16 + r16;
            float bv = 0.f;
            if (BIAS) bv = bias[col];
            #pragma unroll
            for (int r = 0; r < 4; r++) {
                size_t o = (size_t)(row0 + r) * N + col;
                float v = acc[s][ns][r] + bv;
                if (ACT) v = silu_f(v);
                if (RES) v += resid[o];
                Y[o] = v;
            }
        }
    }
}

// ------------------------------------- x_kj *= (rbf @ rbf1) @ rbf2  (E,128)
__global__ __launch_bounds__(256) void mulg_kernel(
    const float* __restrict__ rbf, const float* __restrict__ rbf1,
    const float* __restrict__ rbf2, float* __restrict__ xkj) {
    int gid = blockIdx.x * 256 + threadIdx.x;
    int e = gid >> 7, c = gid & 127;
    float r[6];
    #pragma unroll
    for (int k = 0; k < 6; k++) r[k] = rbf[e * 6 + k];
    float s = 0.f;
    #pragma unroll
    for (int p = 0; p < 8; p++) {
        float g = 0.f;
        #pragma unroll
        for (int k = 0; k < 6; k++) g += r[k] * rbf1[k * 8 + p];
        s += g * rbf2[p * 128 + c];
    }
    xkj[gid] *= s;
}

// ------------------------------- output block scatter: atom += seg(rbfw * m)
__global__ __launch_bounds__(256) void outseg_kernel(
    const float* __restrict__ rbf, const float* __restrict__ orw,
    const float* __restrict__ m, const int* __restrict__ idx_i,
    float* __restrict__ atom) {
    int gid = blockIdx.x * 256 + threadIdx.x;
    int e = gid >> 7, c = gid & 127;
    float s = 0.f;
    #pragma unroll
    for (int k = 0; k < 6; k++) s += rbf[e * 6 + k] * orw[k * 128 + c];
    atomicAdd(&atom[(size_t)idx_i[e] * 128 + c], s * m[gid]);
}

// ---------------------------------------------- final: out[a] += atom . wf
__global__ __launch_bounds__(64) void final_kernel(
    const float* __restrict__ atom, const float* __restrict__ wf,
    float* __restrict__ out) {
    int a = blockIdx.x, l = threadIdx.x;
    float s = 0.f;
    #pragma unroll
    for (int q = 0; q < 4; q++) s += atom[(size_t)a * 256 + q * 64 + l] * wf[q * 64 + l];
    #pragma unroll
    for (int off = 32; off; off >>= 1) s += __shfl_down(s, off, 64);
    if (l == 0) out[a] += s;
}

// ----------------------------------------------------------- triplet kernel
__global__ __launch_bounds__(256, 3) void triplet_kernel(
    const float* __restrict__ dist, const float* __restrict__ angles,
    const int* __restrict__ ekj, const int* __restrict__ rji,
    const float* __restrict__ xdown, const float* __restrict__ sbf1,
    const float* __restrict__ sbf2, float* __restrict__ seg) {
    __shared__ float t8s[256][8];
    __shared__ float s1[336];
    __shared__ float s2[512];
    __shared__ int eks[256];
    __shared__ int rjs[256];
    int tid = threadIdx.x;
    for (int i = tid; i < 336; i += 256) s1[i] = sbf1[i];
    for (int i = tid; i < 512; i += 256) s2[i] = sbf2[i];

    int t = blockIdx.x * 256 + tid;
    int e = ekj[t];
    eks[tid] = e;
    rjs[tid] = rji[t];

    float x = fmaxf(dist[e] * 0.2f, 1e-6f);
    float env = 0.f;
    if (x < 1.0f) {
        float x2 = x * x;
        float x5 = x2 * x2 * x;
        env = 1.0f / x + x5 * (-28.0f + x * (48.0f - 21.0f * x));
    }
    float ct = cosf(angles[t]);
    float Pl[7];
    Pl[0] = 1.f;
    Pl[1] = ct;
    #pragma unroll
    for (int l = 2; l < 7; l++)
        Pl[l] = ((2.f * l - 1.f) * ct * Pl[l - 1] - (l - 1.f) * Pl[l - 2]) / (float)l;
    const float sphc[7] = {0.28209479f, 0.48860251f, 0.63078313f, 0.74635267f,
                           0.84628438f, 0.93560257f, 1.01710723f};
    const float BZ[7][6] = {
        {3.141593f, 6.283185f, 9.424778f, 12.566371f, 15.707963f, 18.849556f},
        {4.493409f, 7.725252f, 10.904122f, 14.066194f, 17.220755f, 20.371303f},
        {5.763459f, 9.095011f, 12.322941f, 15.514603f, 18.689036f, 21.853874f},
        {6.987932f, 10.417119f, 13.698023f, 16.923621f, 20.121806f, 23.304247f},
        {8.182561f, 11.704907f, 15.039665f, 18.301256f, 21.525418f, 24.727566f},
        {9.355812f, 12.966530f, 16.354710f, 19.653152f, 22.904551f, 26.126750f},
        {10.512835f, 14.207392f, 17.647975f, 20.983463f, 24.262768f, 27.507868f}};
    float t8[8] = {0, 0, 0, 0, 0, 0, 0, 0};
    #pragma unroll
    for (int l = 0; l < 7; l++) {
        float coef = env * sphc[l] * Pl[l];
        #pragma unroll
        for (int n = 0; n < 6; n++) {
            float a = BZ[l][n] * x;
            float sa, ca;
            sincosf(a, &sa, &ca);
            float inv = 1.0f / a;
            float j;
            if (l == 0) {
                j = sa * inv;
            } else {
                float jm2 = sa * inv;
                float jm1 = (sa * inv - ca) * inv;
                #pragma unroll
                for (int ll = 2; ll <= l; ll++) {
                    float jn = (2.f * ll - 1.f) * inv * jm1 - jm2;
                    jm2 = jm1;
                    jm1 = jn;
                }
                j = jm1;
            }
            float s = coef * j;
            const float* s1r = &s1[(l * 6 + n) * 8];
            #pragma unroll
            for (int p = 0; p < 8; p++) t8[p] += s * s1r[p];
        }
    }
    #pragma unroll
    for (int p = 0; p < 8; p++) t8s[tid][p] = t8[p];
    __syncthreads();

    int w = tid >> 6, lane = tid & 63;
    float w2[8];
    #pragma unroll
    for (int p = 0; p < 8; p++) w2[p] = s2[p * 64 + lane];
    for (int jj = 0; jj < 64; jj++) {
        int tt = (w << 6) + jj;
        const float4* row = (const float4*)(&t8s[tt][0]);
        float4 q0 = row[0], q1 = row[1];
        float v = q0.x * w2[0] + q0.y * w2[1] + q0.z * w2[2] + q0.w * w2[3] +
                  q1.x * w2[4] + q1.y * w2[5] + q1.z * w2[6] + q1.w * w2[7];
        float y = xdown[(size_t)eks[tt] * 64 + lane] * v;
        atomicAdd(&seg[(size_t)rjs[tt] * 64 + lane], y);
    }
}

// ---------------------------------------------------------------- launcher
extern "C" void kernel_launch(void* const* d_in, const int* in_sizes, int n_in,
                              void* d_out, int out_size, void* d_ws, size_t ws_size,
                              hipStream_t stream) {
    const float* distances   = (const float*)d_in[0];
    const float* angles      = (const float*)d_in[1];
    const float* species_emb = (const float*)d_in[2];
    const float* emb_rbf_w   = (const float*)d_in[3];
    const float* emb_rbf_b   = (const float*)d_in[4];
    const float* emb_dense_w = (const float*)d_in[5];
    const float* emb_dense_b = (const float*)d_in[6];
    const float* out_rbf_w   = (const float*)d_in[7];
    const float* out_up_w    = (const float*)d_in[8];
    const float* out_dense_w = (const float*)d_in[9];
    const float* out_dense_b = (const float*)d_in[10];
    const float* out_final_w = (const float*)d_in[11];
    const float* int_ji_w    = (const float*)d_in[12];
    const float* int_ji_b    = (const float*)d_in[13];
    const float* int_kj_w    = (const float*)d_in[14];
    const float* int_kj_b    = (const float*)d_in[15];
    const float* int_rbf1_w  = (const float*)d_in[16];
    const float* int_rbf2_w  = (const float*)d_in[17];
    const float* int_down_w  = (const float*)d_in[18];
    const float* int_sbf1_w  = (const float*)d_in[19];
    const float* int_sbf2_w  = (const float*)d_in[20];
    const float* int_up_w    = (const float*)d_in[21];
    const float* int_res1_w  = (const float*)d_in[22];
    const float* int_res1_b  = (const float*)d_in[23];
    const float* int_skip_w  = (const float*)d_in[24];
    const float* int_skip_b  = (const float*)d_in[25];
    const float* int_res2_w  = (const float*)d_in[26];
    const float* int_res2_b  = (const float*)d_in[27];
    const int*   species     = (const int*)d_in[28];
    const int*   idx_i       = (const int*)d_in[29];
    const int*   idx_j       = (const int*)d_in[30];
    const int*   reduce_ji   = (const int*)d_in[31];
    const int*   expand_kj   = (const int*)d_in[32];

    const int E = in_sizes[0];       // 65536
    const int T = in_sizes[1];       // 524288
    const int NA = in_sizes[28];     // 4096

    float* ws = (float*)d_ws;
    size_t off = 0;
    float* rbf = ws + off;   off += (size_t)E * 6;
    float* m   = ws + off;   off += (size_t)E * 128;
    float* A   = ws + off;   off += (size_t)E * 128;
    float* B   = ws + off;   off += (size_t)E * 128;
    float* C   = ws + off;   off += (size_t)E * 128;
    float* D   = ws + off;   off += (size_t)E * 64;
    float* HWj = ws + off;   off += 16 * 128;
    float* HWi = ws + off;   off += 16 * 128;
    float* W3  = ws + off;   off += 6 * 128;
    float* b3  = ws + off;   off += 128;
    float* atom1 = ws + off; off += (size_t)NA * 128;
    float* atom2 = ws + off; off += (size_t)NA * 256;
    float* atom3 = ws + off; off += (size_t)NA * 256;
    float* seg = B;

    // bf16 weight planes (hi/lo), [N][K] layout, batched per family
    unsigned short* wb = (unsigned short*)(ws + off);
    size_t wo = 0;
    unsigned short* ji_h = wb + wo;  wo += 4 * 16384;
    unsigned short* ji_l = wb + wo;  wo += 4 * 16384;
    unsigned short* kj_h = wb + wo;  wo += 4 * 16384;
    unsigned short* kj_l = wb + wo;  wo += 4 * 16384;
    unsigned short* dn_h = wb + wo;  wo += 4 * 8192;
    unsigned short* dn_l = wb + wo;  wo += 4 * 8192;
    unsigned short* up_h = wb + wo;  wo += 4 * 8192;
    unsigned short* up_l = wb + wo;  wo += 4 * 8192;
    unsigned short* r1_h = wb + wo;  wo += 8 * 16384;
    unsigned short* r1_l = wb + wo;  wo += 8 * 16384;
    unsigned short* sk_h = wb + wo;  wo += 4 * 16384;
    unsigned short* sk_l = wb + wo;  wo += 4 * 16384;
    unsigned short* r2_h = wb + wo;  wo += 16 * 16384;
    unsigned short* r2_l = wb + wo;  wo += 16 * 16384;
    unsigned short* ou_h = wb + wo;  wo += 5 * 32768;
    unsigned short* ou_l = wb + wo;  wo += 5 * 32768;
    unsigned short* od_h = wb + wo;  wo += 15 * 65536;
    unsigned short* od_l = wb + wo;  wo += 15 * 65536;

    float* out = (float*)d_out;
    hipMemsetAsync(out, 0, (size_t)out_size * sizeof(float), stream);

    // weight conversion (once per launch, ~7 MB total)
    wconv_kernel<<<dim3(4, 4, 4), 256, 0, stream>>>(int_ji_w, ji_h, ji_l, 128, 128);
    wconv_kernel<<<dim3(4, 4, 4), 256, 0, stream>>>(int_kj_w, kj_h, kj_l, 128, 128);
    wconv_kernel<<<dim3(2, 4, 4), 256, 0, stream>>>(int_down_w, dn_h, dn_l, 128, 64);
    wconv_kernel<<<dim3(4, 2, 4), 256, 0, stream>>>(int_up_w, up_h, up_l, 64, 128);
    wconv_kernel<<<dim3(4, 4, 8), 256, 0, stream>>>(int_res1_w, r1_h, r1_l, 128, 128);
    wconv_kernel<<<dim3(4, 4, 4), 256, 0, stream>>>(int_skip_w, sk_h, sk_l, 128, 128);
    wconv_kernel<<<dim3(4, 4, 16), 256, 0, stream>>>(int_res2_w, r2_h, r2_l, 128, 128);
    wconv_kernel<<<dim3(8, 4, 5), 256, 0, stream>>>(out_up_w, ou_h, ou_l, 128, 256);
    wconv_kernel<<<dim3(8, 8, 15), 256, 0, stream>>>(out_dense_w, od_h, od_l, 256, 256);

    rbf_kernel<<<E / 256, 256, 0, stream>>>(distances, rbf, E);
    embed_pre_kernel<<<1, 128, 0, stream>>>(species_emb, emb_rbf_w, emb_rbf_b,
                                            emb_dense_w, HWj, HWi, W3, b3);
    embed_kernel<<<E * 128 / 256, 256, 0, stream>>>(rbf, species, idx_i, idx_j,
                                                    HWj, HWi, W3, b3, emb_dense_b, m);

    auto outblock = [&](int i, const float* msg) {
        hipMemsetAsync(atom1, 0, (size_t)NA * 128 * sizeof(float), stream);
        outseg_kernel<<<E * 128 / 256, 256, 0, stream>>>(
            rbf, out_rbf_w + (size_t)i * 6 * 128, msg, idx_i, atom1);
        mfma_gemm<128, 0, 0, 0><<<dim3(NA / 128, 2), 512, 0, stream>>>(
            atom1, ou_h + (size_t)i * 32768, ou_l + (size_t)i * 32768,
            nullptr, nullptr, atom2, NA, 128, 256);
        mfma_gemm<128, 1, 1, 0><<<dim3(NA / 128, 2), 512, 0, stream>>>(
            atom2, od_h + ((size_t)i * 3 + 0) * 65536, od_l + ((size_t)i * 3 + 0) * 65536,
            out_dense_b + ((size_t)i * 3 + 0) * 256, nullptr, atom3, NA, 256, 256);
        mfma_gemm<128, 1, 1, 0><<<dim3(NA / 128, 2), 512, 0, stream>>>(
            atom3, od_h + ((size_t)i * 3 + 1) * 65536, od_l + ((size_t)i * 3 + 1) * 65536,
            out_dense_b + ((size_t)i * 3 + 1) * 256, nullptr, atom2, NA, 256, 256);
        mfma_gemm<128, 1, 1, 0><<<dim3(NA / 128, 2), 512, 0, stream>>>(
            atom2, od_h + ((size_t)i * 3 + 2) * 65536, od_l + ((size_t)i * 3 + 2) * 65536,
            out_dense_b + ((size_t)i * 3 + 2) * 256, nullptr, atom3, NA, 256, 256);
        final_kernel<<<NA, 64, 0, stream>>>(atom3, out_final_w + (size_t)i * 256, out);
    };

    outblock(0, m);

    for (int i = 0; i < 4; i++) {
        // x_ji = silu(m @ ji + b)
        mfma_gemm<128, 1, 1, 0><<<dim3(E / 128, 1), 512, 0, stream>>>(
            m, ji_h + (size_t)i * 16384, ji_l + (size_t)i * 16384,
            int_ji_b + (size_t)i * 128, nullptr, A, E, 128, 128);
        // x_kj = silu(m @ kj + b)
        mfma_gemm<128, 1, 1, 0><<<dim3(E / 128, 1), 512, 0, stream>>>(
            m, kj_h + (size_t)i * 16384, kj_l + (size_t)i * 16384,
            int_kj_b + (size_t)i * 128, nullptr, B, E, 128, 128);
        // x_kj *= (rbf @ rbf1) @ rbf2
        mulg_kernel<<<E * 128 / 256, 256, 0, stream>>>(
            rbf, int_rbf1_w + (size_t)i * 48, int_rbf2_w + (size_t)i * 8 * 128, B);
        // xdown = silu(x_kj @ down)
        mfma_gemm<64, 1, 0, 0><<<dim3(E / 128, 1), 256, 0, stream>>>(
            B, dn_h + (size_t)i * 8192, dn_l + (size_t)i * 8192,
            nullptr, nullptr, D, E, 128, 64);
        // triplet scatter into seg (reuses B)
        hipMemsetAsync(seg, 0, (size_t)E * 64 * sizeof(float), stream);
        triplet_kernel<<<T / 256, 256, 0, stream>>>(
            distances, angles, expand_kj, reduce_ji, D,
            int_sbf1_w + (size_t)i * 42 * 8, int_sbf2_w + (size_t)i * 8 * 64, seg);
        // hm = x_ji + silu(seg @ up)
        mfma_gemm<128, 1, 0, 1><<<dim3(E / 128, 1), 512, 0, stream>>>(
            seg, up_h + (size_t)i * 8192, up_l + (size_t)i * 8192,
            nullptr, A, C, E, 64, 128);
        // res-before
        mfma_gemm<128, 1, 1, 0><<<dim3(E / 128, 1), 512, 0, stream>>>(
            C, r1_h + ((size_t)i * 2 + 0) * 16384, r1_l + ((size_t)i * 2 + 0) * 16384,
            int_res1_b + ((size_t)i * 2 + 0) * 128, nullptr, A, E, 128, 128);
        mfma_gemm<128, 1, 1, 1><<<dim3(E / 128, 1), 512, 0, stream>>>(
            A, r1_h + ((size_t)i * 2 + 1) * 16384, r1_l + ((size_t)i * 2 + 1) * 16384,
            int_res1_b + ((size_t)i * 2 + 1) * 128, C, B, E, 128, 128);
        // m = silu(hm @ skip + b) + m
        mfma_gemm<128, 1, 1, 1><<<dim3(E / 128, 1), 512, 0, stream>>>(
            B, sk_h + (size_t)i * 16384, sk_l + (size_t)i * 16384,
            int_skip_b + (size_t)i * 128, m, m, E, 128, 128);
        // res-after x2
        for (int r = 0; r < 2; r++) {
            mfma_gemm<128, 1, 1, 0><<<dim3(E / 128, 1), 512, 0, stream>>>(
                m, r2_h + (((size_t)i * 2 + r) * 2 + 0) * 16384,
                r2_l + (((size_t)i * 2 + r) * 2 + 0) * 16384,
                int_res2_b + (((size_t)i * 2 + r) * 2 + 0) * 128, nullptr, A, E, 128, 128);
            mfma_gemm<128, 1, 1, 1><<<dim3(E / 128, 1), 512, 0, stream>>>(
                A, r2_h + (((size_t)i * 2 + r) * 2 + 1) * 16384,
                r2_l + (((size_t)i * 2 + r) * 2 + 1) * 16384,
                int_res2_b + (((size_t)i * 2 + r) * 2 + 1) * 128, m, m, E, 128, 128);
        }
        outblock(i + 1, m);
    }
}

// Round 3
// 1843.890 us; speedup vs baseline: 2.0385x; 1.7191x over previous
//
#include <hip/hip_runtime.h>
#include <cmath>

typedef __attribute__((ext_vector_type(8))) short bfrag;   // 8 bf16 = 4 VGPRs
typedef __attribute__((ext_vector_type(4))) float f32x4;

// ---------------------------------------------------------------- helpers
__device__ __forceinline__ float silu_f(float x) {
    return x / (1.0f + __expf(-x));
}
__device__ __forceinline__ unsigned short f2bf(float f) {
    unsigned u = __float_as_uint(f);
    unsigned r = (u + 0x7fff + ((u >> 16) & 1)) >> 16;
    return (unsigned short)r;
}
__device__ __forceinline__ float bf2f(unsigned short h) {
    return __uint_as_float(((unsigned)h) << 16);
}
__device__ __forceinline__ unsigned packbf2(float lo, float hi) {
    return ((unsigned)f2bf(hi) << 16) | (unsigned)f2bf(lo);
}

// ---------------------------------------------------------------- rbf (E,6)
__global__ __launch_bounds__(256) void rbf_kernel(const float* __restrict__ d,
                                                  float* __restrict__ rbf, int E) {
    int e = blockIdx.x * 256 + threadIdx.x;
    if (e >= E) return;
    float x = d[e] * 0.2f;               // d / CUTOFF
    float env = 0.0f;
    if (x < 1.0f) {
        float x2 = x * x;
        float x5 = x2 * x2 * x;
        env = 1.0f / x + x5 * (-28.0f + x * (48.0f - 21.0f * x));
    }
    const float SQ = 0.63245553f;        // sqrt(2/5)
    float px = 3.14159265358979f * x;
    #pragma unroll
    for (int n = 1; n <= 6; n++) {
        rbf[e * 6 + n - 1] = SQ * env * sinf(px * (float)n);
    }
}

// ------------------------------------------- embedding precompute (1 block)
__global__ __launch_bounds__(128) void embed_pre_kernel(
    const float* __restrict__ se, const float* __restrict__ erw,
    const float* __restrict__ erb, const float* __restrict__ edw,
    float* __restrict__ HWj, float* __restrict__ HWi,
    float* __restrict__ W3, float* __restrict__ b3) {
    int c = threadIdx.x;
    for (int s = 0; s < 16; s++) {
        float aj = 0.f, ai = 0.f;
        for (int k = 0; k < 64; k++) {
            float h = se[s * 64 + k];
            aj += h * edw[k * 128 + c];
            ai += h * edw[(64 + k) * 128 + c];
        }
        HWj[s * 128 + c] = aj;
        HWi[s * 128 + c] = ai;
    }
    for (int r = 0; r < 6; r++) {
        float a = 0.f;
        for (int k = 0; k < 128; k++) a += erw[r * 128 + k] * edw[(128 + k) * 128 + c];
        W3[r * 128 + c] = a;
    }
    float a = 0.f;
    for (int k = 0; k < 128; k++) a += erb[k] * edw[(128 + k) * 128 + c];
    b3[c] = a;
}

// ---------------------------------------------------------------- m (E,128)
__global__ __launch_bounds__(256) void embed_kernel(
    const float* __restrict__ rbf, const int* __restrict__ species,
    const int* __restrict__ idx_i, const int* __restrict__ idx_j,
    const float* __restrict__ HWj, const float* __restrict__ HWi,
    const float* __restrict__ W3, const float* __restrict__ b3,
    const float* __restrict__ edb, float* __restrict__ m) {
    int gid = blockIdx.x * 256 + threadIdx.x;
    int e = gid >> 7, c = gid & 127;
    int sj = species[idx_j[e]];
    int si = species[idx_i[e]];
    float v = HWj[sj * 128 + c] + HWi[si * 128 + c] + b3[c] + edb[c];
    #pragma unroll
    for (int k = 0; k < 6; k++) v += rbf[e * 6 + k] * W3[k * 128 + c];
    m[gid] = silu_f(v);
}

// -------------------------------------- weight transpose+split (batched)
// in:  W [B][K][N] fp32 ;  out: hi/lo [B][N][K] bf16 planes
__global__ __launch_bounds__(256) void wconv_kernel(
    const float* __restrict__ W, unsigned short* __restrict__ hi,
    unsigned short* __restrict__ lo, int K, int N) {
    __shared__ float t[32][33];
    int b = blockIdx.z;
    int n0 = blockIdx.x * 32, k0 = blockIdx.y * 32;
    const float* Wb = W + (size_t)b * K * N;
    int tid = threadIdx.x;
    int r = tid >> 3, cg = tid & 7;
    float4 v = *(const float4*)&Wb[(size_t)(k0 + r) * N + n0 + cg * 4];
    t[r][cg * 4 + 0] = v.x;
    t[r][cg * 4 + 1] = v.y;
    t[r][cg * 4 + 2] = v.z;
    t[r][cg * 4 + 3] = v.w;
    __syncthreads();
    int nl = tid >> 3, kg = tid & 7;
    short4 h4, l4;
    float f0 = t[kg * 4 + 0][nl], f1 = t[kg * 4 + 1][nl];
    float f2 = t[kg * 4 + 2][nl], f3 = t[kg * 4 + 3][nl];
    unsigned short h;
    h = f2bf(f0); h4.x = (short)h; l4.x = (short)f2bf(f0 - bf2f(h));
    h = f2bf(f1); h4.y = (short)h; l4.y = (short)f2bf(f1 - bf2f(h));
    h = f2bf(f2); h4.z = (short)h; l4.z = (short)f2bf(f2 - bf2f(h));
    h = f2bf(f3); h4.w = (short)h; l4.w = (short)f2bf(f3 - bf2f(h));
    size_t o = ((size_t)b * N + n0 + nl) * K + k0 + kg * 4;
    *(short4*)&hi[o] = h4;
    *(short4*)&lo[o] = l4;
}

// ---------------------------------------------- split-bf16 MFMA dense GEMM
template <int BN, int ACT, int BIAS, int RES>
__global__ __launch_bounds__(BN * 4) void mfma_gemm(
    const float* __restrict__ X, const unsigned short* __restrict__ Whi,
    const unsigned short* __restrict__ Wlo,
    const float* __restrict__ bias, const float* __restrict__ resid,
    float* __restrict__ Y, int M, int K, int N) {
    constexpr int T = BN * 4;        // threads
    constexpr int WC = BN / 32;      // wave columns
    constexpr int AP = 1024 / T;     // float4 loads per thread for A tile
    __shared__ unsigned short Ah[128 * 40];
    __shared__ unsigned short Al[128 * 40];
    __shared__ unsigned short Bh[BN * 40];
    __shared__ unsigned short Bl[BN * 40];

    int tid = threadIdx.x;
    int bm = blockIdx.x * 128, bn = blockIdx.y * BN;
    int wid = tid >> 6, lane = tid & 63;
    int wr = wid / WC, wc = wid % WC;
    int r16 = lane & 15, kg = lane >> 4;

    f32x4 acc[4][2];
    #pragma unroll
    for (int s = 0; s < 4; s++)
        #pragma unroll
        for (int ns = 0; ns < 2; ns++) acc[s][ns] = (f32x4)0.f;

    int brow = tid >> 2, bkg = tid & 3;

    for (int k0 = 0; k0 < K; k0 += 32) {
        float4 av[AP];
        #pragma unroll
        for (int p = 0; p < AP; p++) {
            int idx = tid + p * T;
            int row = idx >> 3, cg = idx & 7;
            av[p] = *(const float4*)&X[(size_t)(bm + row) * K + k0 + cg * 4];
        }
        float4 bh = *(const float4*)&Whi[(size_t)(bn + brow) * K + k0 + bkg * 8];
        float4 bl = *(const float4*)&Wlo[(size_t)(bn + brow) * K + k0 + bkg * 8];
        __syncthreads();
        #pragma unroll
        for (int p = 0; p < AP; p++) {
            int idx = tid + p * T;
            int row = idx >> 3, cg = idx & 7;
            float fv[4] = {av[p].x, av[p].y, av[p].z, av[p].w};
            short4 h4, l4;
            unsigned short h;
            h = f2bf(fv[0]); h4.x = (short)h; l4.x = (short)f2bf(fv[0] - bf2f(h));
            h = f2bf(fv[1]); h4.y = (short)h; l4.y = (short)f2bf(fv[1] - bf2f(h));
            h = f2bf(fv[2]); h4.z = (short)h; l4.z = (short)f2bf(fv[2] - bf2f(h));
            h = f2bf(fv[3]); h4.w = (short)h; l4.w = (short)f2bf(fv[3] - bf2f(h));
            *(short4*)&Ah[row * 40 + cg * 4] = h4;
            *(short4*)&Al[row * 40 + cg * 4] = l4;
        }
        *(float4*)&Bh[brow * 40 + bkg * 8] = bh;
        *(float4*)&Bl[brow * 40 + bkg * 8] = bl;
        __syncthreads();

        bfrag bhf[2], blf[2];
        #pragma unroll
        for (int ns = 0; ns < 2; ns++) {
            int br = wc * 32 + ns * 16 + r16;
            bhf[ns] = *(const bfrag*)&Bh[br * 40 + kg * 8];
            blf[ns] = *(const bfrag*)&Bl[br * 40 + kg * 8];
        }
        #pragma unroll
        for (int s = 0; s < 4; s++) {
            int ar = wr * 64 + s * 16 + r16;
            bfrag ah = *(const bfrag*)&Ah[ar * 40 + kg * 8];
            bfrag al = *(const bfrag*)&Al[ar * 40 + kg * 8];
            #pragma unroll
            for (int ns = 0; ns < 2; ns++) {
                acc[s][ns] = __builtin_amdgcn_mfma_f32_16x16x32_bf16(ah, bhf[ns], acc[s][ns], 0, 0, 0);
                acc[s][ns] = __builtin_amdgcn_mfma_f32_16x16x32_bf16(ah, blf[ns], acc[s][ns], 0, 0, 0);
                acc[s][ns] = __builtin_amdgcn_mfma_f32_16x16x32_bf16(al, bhf[ns], acc[s][ns], 0, 0, 0);
            }
        }
    }

    #pragma unroll
    for (int s = 0; s < 4; s++) {
        int row0 = bm + wr * 64 + s * 16 + kg * 4;
        #pragma unroll
        for (int ns = 0; ns < 2; ns++) {
            int col = bn + wc * 32 + ns * 16 + r16;
            float bv = 0.f;
            if (BIAS) bv = bias[col];
            #pragma unroll
            for (int r = 0; r < 4; r++) {
                size_t o = (size_t)(row0 + r) * N + col;
                float v = acc[s][ns][r] + bv;
                if (ACT) v = silu_f(v);
                if (RES) v += resid[o];
                Y[o] = v;
            }
        }
    }
}

// ------------------------------------- x_kj *= (rbf @ rbf1) @ rbf2  (E,128)
__global__ __launch_bounds__(256) void mulg_kernel(
    const float* __restrict__ rbf, const float* __restrict__ rbf1,
    const float* __restrict__ rbf2, float* __restrict__ xkj) {
    int gid = blockIdx.x * 256 + threadIdx.x;
    int e = gid >> 7, c = gid & 127;
    float r[6];
    #pragma unroll
    for (int k = 0; k < 6; k++) r[k] = rbf[e * 6 + k];
    float s = 0.f;
    #pragma unroll
    for (int p = 0; p < 8; p++) {
        float g = 0.f;
        #pragma unroll
        for (int k = 0; k < 6; k++) g += r[k] * rbf1[k * 8 + p];
        s += g * rbf2[p * 128 + c];
    }
    xkj[gid] *= s;
}

// ------------------------------- output block scatter: atom += seg(rbfw * m)
__global__ __launch_bounds__(256) void outseg_kernel(
    const float* __restrict__ rbf, const float* __restrict__ orw,
    const float* __restrict__ m, const int* __restrict__ idx_i,
    float* __restrict__ atom) {
    int gid = blockIdx.x * 256 + threadIdx.x;
    int e = gid >> 7, c = gid & 127;
    float s = 0.f;
    #pragma unroll
    for (int k = 0; k < 6; k++) s += rbf[e * 6 + k] * orw[k * 128 + c];
    atomicAdd(&atom[(size_t)idx_i[e] * 128 + c], s * m[gid]);
}

// ---------------------------------------------- final: out[a] += atom . wf
__global__ __launch_bounds__(64) void final_kernel(
    const float* __restrict__ atom, const float* __restrict__ wf,
    float* __restrict__ out) {
    int a = blockIdx.x, l = threadIdx.x;
    float s = 0.f;
    #pragma unroll
    for (int q = 0; q < 4; q++) s += atom[(size_t)a * 256 + q * 64 + l] * wf[q * 64 + l];
    #pragma unroll
    for (int off = 32; off; off >>= 1) s += __shfl_down(s, off, 64);
    if (l == 0) out[a] += s;
}

// ===================== triplet phase: counting sort by reduce_to_ji =======
__global__ __launch_bounds__(256) void hist_kernel(const int* __restrict__ rji,
                                                   int* __restrict__ hist) {
    int t = blockIdx.x * 256 + threadIdx.x;
    atomicAdd(&hist[rji[t]], 1);
}

__global__ __launch_bounds__(256) void scan1_kernel(const int* __restrict__ hist,
                                                    int* __restrict__ bsum) {
    __shared__ int s[256];
    int i = threadIdx.x;
    s[i] = hist[blockIdx.x * 256 + i];
    __syncthreads();
    for (int o = 128; o; o >>= 1) {
        if (i < o) s[i] += s[i + o];
        __syncthreads();
    }
    if (!i) bsum[blockIdx.x] = s[0];
}

__global__ __launch_bounds__(256) void scan2_kernel(const int* __restrict__ bsum,
                                                    int* __restrict__ boff) {
    __shared__ int s[256];
    int i = threadIdx.x;
    int own = bsum[i];
    s[i] = own;
    __syncthreads();
    for (int o = 1; o < 256; o <<= 1) {
        int v = (i >= o) ? s[i - o] : 0;
        __syncthreads();
        s[i] += v;
        __syncthreads();
    }
    boff[i] = s[i] - own;   // exclusive
}

__global__ __launch_bounds__(256) void scan3_kernel(const int* __restrict__ hist,
                                                    const int* __restrict__ boff,
                                                    int* __restrict__ rows,
                                                    int* __restrict__ cursor, int T) {
    __shared__ int s[256];
    int i = threadIdx.x, b = blockIdx.x;
    int h = hist[b * 256 + i];
    s[i] = h;
    __syncthreads();
    for (int o = 1; o < 256; o <<= 1) {
        int v = (i >= o) ? s[i - o] : 0;
        __syncthreads();
        s[i] += v;
        __syncthreads();
    }
    int excl = s[i] - h + boff[b];
    rows[b * 256 + i] = excl;
    cursor[b * 256 + i] = excl;
    if (b == gridDim.x - 1 && i == 255) rows[b * 256 + 256] = T;
}

__global__ __launch_bounds__(256) void scatter_kernel(
    const int* __restrict__ rji, const int* __restrict__ ekj,
    int* __restrict__ cursor, int* __restrict__ perm, int* __restrict__ ekjs) {
    int t = blockIdx.x * 256 + threadIdx.x;
    int r = rji[t];
    int pos = atomicAdd(&cursor[r], 1);
    perm[pos] = t;
    ekjs[pos] = ekj[t];
}

// ------------- sbf precompute: trig once, contract with all 4 blocks' sbf1
// t32 layout: 4 planes of [T][8] bf16
__global__ __launch_bounds__(256) void sbf_pre_kernel(
    const float* __restrict__ dist, const float* __restrict__ angles,
    const int* __restrict__ perm, const int* __restrict__ ekjs,
    const float* __restrict__ sbf1_all, unsigned short* __restrict__ t32, int T) {
    __shared__ float s1[1344];               // 4 blocks x 42 x 8
    int tid = threadIdx.x;
    for (int i = tid; i < 1344; i += 256) s1[i] = sbf1_all[i];
    __syncthreads();

    int pos = blockIdx.x * 256 + tid;
    int t = perm[pos];
    int e = ekjs[pos];
    float x = fmaxf(dist[e] * 0.2f, 1e-6f);
    float env = 0.f;
    if (x < 1.0f) {
        float x2 = x * x;
        float x5 = x2 * x2 * x;
        env = 1.0f / x + x5 * (-28.0f + x * (48.0f - 21.0f * x));
    }
    float ct = cosf(angles[t]);
    float Pl[7];
    Pl[0] = 1.f;
    Pl[1] = ct;
    #pragma unroll
    for (int l = 2; l < 7; l++)
        Pl[l] = ((2.f * l - 1.f) * ct * Pl[l - 1] - (l - 1.f) * Pl[l - 2]) / (float)l;
    const float sphc[7] = {0.28209479f, 0.48860251f, 0.63078313f, 0.74635267f,
                           0.84628438f, 0.93560257f, 1.01710723f};
    const float BZ[7][6] = {
        {3.141593f, 6.283185f, 9.424778f, 12.566371f, 15.707963f, 18.849556f},
        {4.493409f, 7.725252f, 10.904122f, 14.066194f, 17.220755f, 20.371303f},
        {5.763459f, 9.095011f, 12.322941f, 15.514603f, 18.689036f, 21.853874f},
        {6.987932f, 10.417119f, 13.698023f, 16.923621f, 20.121806f, 23.304247f},
        {8.182561f, 11.704907f, 15.039665f, 18.301256f, 21.525418f, 24.727566f},
        {9.355812f, 12.966530f, 16.354710f, 19.653152f, 22.904551f, 26.126750f},
        {10.512835f, 14.207392f, 17.647975f, 20.983463f, 24.262768f, 27.507868f}};
    float sbf[42];
    #pragma unroll
    for (int l = 0; l < 7; l++) {
        float coef = env * sphc[l] * Pl[l];
        #pragma unroll
        for (int n = 0; n < 6; n++) {
            float a = BZ[l][n] * x;
            float sa, ca;
            sincosf(a, &sa, &ca);
            float inv = 1.0f / a;
            float j;
            if (l == 0) {
                j = sa * inv;
            } else {
                float jm2 = sa * inv;
                float jm1 = (sa * inv - ca) * inv;
                #pragma unroll
                for (int ll = 2; ll <= l; ll++) {
                    float jn = (2.f * ll - 1.f) * inv * jm1 - jm2;
                    jm2 = jm1;
                    jm1 = jn;
                }
                j = jm1;
            }
            sbf[l * 6 + n] = coef * j;
        }
    }
    float acc[32];
    #pragma unroll
    for (int q = 0; q < 32; q++) acc[q] = 0.f;
    #pragma unroll
    for (int k = 0; k < 42; k++) {
        float sv = sbf[k];
        #pragma unroll
        for (int b = 0; b < 4; b++)
            #pragma unroll
            for (int p = 0; p < 8; p++)
                acc[b * 8 + p] = fmaf(sv, s1[b * 336 + k * 8 + p], acc[b * 8 + p]);
    }
    #pragma unroll
    for (int b = 0; b < 4; b++) {
        uint4 u;
        u.x = packbf2(acc[b * 8 + 0], acc[b * 8 + 1]);
        u.y = packbf2(acc[b * 8 + 2], acc[b * 8 + 3]);
        u.z = packbf2(acc[b * 8 + 4], acc[b * 8 + 5]);
        u.w = packbf2(acc[b * 8 + 6], acc[b * 8 + 7]);
        *(uint4*)&t32[((size_t)b * T + pos) * 8] = u;
    }
}

// ------------- per-block gather reduce: one wave per target edge, no atomics
// seg[e][c] = sum_{pos in [rows[e],rows[e+1])} (t8[pos].sbf2[:,c]) * xdown[ekjs[pos]][c]
__global__ __launch_bounds__(256) void seg_gather_kernel(
    const unsigned short* __restrict__ t32p, const int* __restrict__ ekjs,
    const int* __restrict__ rows, const float* __restrict__ xdown,
    const float* __restrict__ sbf2, float* __restrict__ seg, int E) {
    int gid = blockIdx.x * 256 + threadIdx.x;
    int e = gid >> 6, lane = gid & 63;
    if (e >= E) return;
    float w2[8];
    #pragma unroll
    for (int p = 0; p < 8; p++) w2[p] = sbf2[p * 64 + lane];
    int p0 = rows[e], p1 = rows[e + 1];
    float acc = 0.f;
    for (int pos = p0; pos < p1; ++pos) {
        uint4 a = *(const uint4*)&t32p[(size_t)pos * 8];
        float v = __uint_as_float(a.x << 16) * w2[0] + __uint_as_float(a.x & 0xffff0000u) * w2[1]
                + __uint_as_float(a.y << 16) * w2[2] + __uint_as_float(a.y & 0xffff0000u) * w2[3]
                + __uint_as_float(a.z << 16) * w2[4] + __uint_as_float(a.z & 0xffff0000u) * w2[5]
                + __uint_as_float(a.w << 16) * w2[6] + __uint_as_float(a.w & 0xffff0000u) * w2[7];
        acc = fmaf(v, xdown[(size_t)ekjs[pos] * 64 + lane], acc);
    }
    seg[(size_t)e * 64 + lane] = acc;
}

// ---------------------------------------------------------------- launcher
extern "C" void kernel_launch(void* const* d_in, const int* in_sizes, int n_in,
                              void* d_out, int out_size, void* d_ws, size_t ws_size,
                              hipStream_t stream) {
    const float* distances   = (const float*)d_in[0];
    const float* angles      = (const float*)d_in[1];
    const float* species_emb = (const float*)d_in[2];
    const float* emb_rbf_w   = (const float*)d_in[3];
    const float* emb_rbf_b   = (const float*)d_in[4];
    const float* emb_dense_w = (const float*)d_in[5];
    const float* emb_dense_b = (const float*)d_in[6];
    const float* out_rbf_w   = (const float*)d_in[7];
    const float* out_up_w    = (const float*)d_in[8];
    const float* out_dense_w = (const float*)d_in[9];
    const float* out_dense_b = (const float*)d_in[10];
    const float* out_final_w = (const float*)d_in[11];
    const float* int_ji_w    = (const float*)d_in[12];
    const float* int_ji_b    = (const float*)d_in[13];
    const float* int_kj_w    = (const float*)d_in[14];
    const float* int_kj_b    = (const float*)d_in[15];
    const float* int_rbf1_w  = (const float*)d_in[16];
    const float* int_rbf2_w  = (const float*)d_in[17];
    const float* int_down_w  = (const float*)d_in[18];
    const float* int_sbf1_w  = (const float*)d_in[19];
    const float* int_sbf2_w  = (const float*)d_in[20];
    const float* int_up_w    = (const float*)d_in[21];
    const float* int_res1_w  = (const float*)d_in[22];
    const float* int_res1_b  = (const float*)d_in[23];
    const float* int_skip_w  = (const float*)d_in[24];
    const float* int_skip_b  = (const float*)d_in[25];
    const float* int_res2_w  = (const float*)d_in[26];
    const float* int_res2_b  = (const float*)d_in[27];
    const int*   species     = (const int*)d_in[28];
    const int*   idx_i       = (const int*)d_in[29];
    const int*   idx_j       = (const int*)d_in[30];
    const int*   reduce_ji   = (const int*)d_in[31];
    const int*   expand_kj   = (const int*)d_in[32];

    const int E = in_sizes[0];       // 65536
    const int T = in_sizes[1];       // 524288
    const int NA = in_sizes[28];     // 4096

    float* ws = (float*)d_ws;
    size_t off = 0;
    float* rbf = ws + off;   off += (size_t)E * 6;
    float* m   = ws + off;   off += (size_t)E * 128;
    float* A   = ws + off;   off += (size_t)E * 128;
    float* B   = ws + off;   off += (size_t)E * 128;
    float* C   = ws + off;   off += (size_t)E * 128;
    float* D   = ws + off;   off += (size_t)E * 64;
    float* HWj = ws + off;   off += 16 * 128;
    float* HWi = ws + off;   off += 16 * 128;
    float* W3  = ws + off;   off += 6 * 128;
    float* b3  = ws + off;   off += 128;
    float* atom1 = ws + off; off += (size_t)NA * 128;
    float* atom2 = ws + off; off += (size_t)NA * 256;
    float* atom3 = ws + off; off += (size_t)NA * 256;
    float* seg = B;

    // bf16 weight planes (hi/lo), [N][K] layout, batched per family
    unsigned short* wb = (unsigned short*)(ws + off);
    size_t wo = 0;
    unsigned short* ji_h = wb + wo;  wo += 4 * 16384;
    unsigned short* ji_l = wb + wo;  wo += 4 * 16384;
    unsigned short* kj_h = wb + wo;  wo += 4 * 16384;
    unsigned short* kj_l = wb + wo;  wo += 4 * 16384;
    unsigned short* dn_h = wb + wo;  wo += 4 * 8192;
    unsigned short* dn_l = wb + wo;  wo += 4 * 8192;
    unsigned short* up_h = wb + wo;  wo += 4 * 8192;
    unsigned short* up_l = wb + wo;  wo += 4 * 8192;
    unsigned short* r1_h = wb + wo;  wo += 8 * 16384;
    unsigned short* r1_l = wb + wo;  wo += 8 * 16384;
    unsigned short* sk_h = wb + wo;  wo += 4 * 16384;
    unsigned short* sk_l = wb + wo;  wo += 4 * 16384;
    unsigned short* r2_h = wb + wo;  wo += 16 * 16384;
    unsigned short* r2_l = wb + wo;  wo += 16 * 16384;
    unsigned short* ou_h = wb + wo;  wo += 5 * 32768;
    unsigned short* ou_l = wb + wo;  wo += 5 * 32768;
    unsigned short* od_h = wb + wo;  wo += 15 * 65536;
    unsigned short* od_l = wb + wo;  wo += 15 * 65536;
    // triplet-sort structures (after weights; wo is 16B-aligned here)
    unsigned short* t32 = wb + wo;   wo += (size_t)4 * T * 8;
    int* ip    = (int*)(wb + wo);
    size_t io  = 0;
    int* hist   = ip + io;  io += E;
    int* rows   = ip + io;  io += E + 64;
    int* cursor = ip + io;  io += E;
    int* bsum   = ip + io;  io += 256;
    int* boff   = ip + io;  io += 256;
    int* perm   = ip + io;  io += T;
    int* ekjs   = ip + io;  io += T;

    float* out = (float*)d_out;
    hipMemsetAsync(out, 0, (size_t)out_size * sizeof(float), stream);

    // ---- triplet counting sort + basis precompute (once per launch)
    hipMemsetAsync(hist, 0, (size_t)E * sizeof(int), stream);
    hist_kernel<<<T / 256, 256, 0, stream>>>(reduce_ji, hist);
    scan1_kernel<<<E / 256, 256, 0, stream>>>(hist, bsum);
    scan2_kernel<<<1, 256, 0, stream>>>(bsum, boff);
    scan3_kernel<<<E / 256, 256, 0, stream>>>(hist, boff, rows, cursor, T);
    scatter_kernel<<<T / 256, 256, 0, stream>>>(reduce_ji, expand_kj, cursor, perm, ekjs);
    sbf_pre_kernel<<<T / 256, 256, 0, stream>>>(distances, angles, perm, ekjs,
                                                int_sbf1_w, t32, T);

    // weight conversion (once per launch, ~7 MB total)
    wconv_kernel<<<dim3(4, 4, 4), 256, 0, stream>>>(int_ji_w, ji_h, ji_l, 128, 128);
    wconv_kernel<<<dim3(4, 4, 4), 256, 0, stream>>>(int_kj_w, kj_h, kj_l, 128, 128);
    wconv_kernel<<<dim3(2, 4, 4), 256, 0, stream>>>(int_down_w, dn_h, dn_l, 128, 64);
    wconv_kernel<<<dim3(4, 2, 4), 256, 0, stream>>>(int_up_w, up_h, up_l, 64, 128);
    wconv_kernel<<<dim3(4, 4, 8), 256, 0, stream>>>(int_res1_w, r1_h, r1_l, 128, 128);
    wconv_kernel<<<dim3(4, 4, 4), 256, 0, stream>>>(int_skip_w, sk_h, sk_l, 128, 128);
    wconv_kernel<<<dim3(4, 4, 16), 256, 0, stream>>>(int_res2_w, r2_h, r2_l, 128, 128);
    wconv_kernel<<<dim3(8, 4, 5), 256, 0, stream>>>(out_up_w, ou_h, ou_l, 128, 256);
    wconv_kernel<<<dim3(8, 8, 15), 256, 0, stream>>>(out_dense_w, od_h, od_l, 256, 256);

    rbf_kernel<<<E / 256, 256, 0, stream>>>(distances, rbf, E);
    embed_pre_kernel<<<1, 128, 0, stream>>>(species_emb, emb_rbf_w, emb_rbf_b,
                                            emb_dense_w, HWj, HWi, W3, b3);
    embed_kernel<<<E * 128 / 256, 256, 0, stream>>>(rbf, species, idx_i, idx_j,
                                                    HWj, HWi, W3, b3, emb_dense_b, m);

    auto outblock = [&](int i, const float* msg) {
        hipMemsetAsync(atom1, 0, (size_t)NA * 128 * sizeof(float), stream);
        outseg_kernel<<<E * 128 / 256, 256, 0, stream>>>(
            rbf, out_rbf_w + (size_t)i * 6 * 128, msg, idx_i, atom1);
        mfma_gemm<128, 0, 0, 0><<<dim3(NA / 128, 2), 512, 0, stream>>>(
            atom1, ou_h + (size_t)i * 32768, ou_l + (size_t)i * 32768,
            nullptr, nullptr, atom2, NA, 128, 256);
        mfma_gemm<128, 1, 1, 0><<<dim3(NA / 128, 2), 512, 0, stream>>>(
            atom2, od_h + ((size_t)i * 3 + 0) * 65536, od_l + ((size_t)i * 3 + 0) * 65536,
            out_dense_b + ((size_t)i * 3 + 0) * 256, nullptr, atom3, NA, 256, 256);
        mfma_gemm<128, 1, 1, 0><<<dim3(NA / 128, 2), 512, 0, stream>>>(
            atom3, od_h + ((size_t)i * 3 + 1) * 65536, od_l + ((size_t)i * 3 + 1) * 65536,
            out_dense_b + ((size_t)i * 3 + 1) * 256, nullptr, atom2, NA, 256, 256);
        mfma_gemm<128, 1, 1, 0><<<dim3(NA / 128, 2), 512, 0, stream>>>(
            atom2, od_h + ((size_t)i * 3 + 2) * 65536, od_l + ((size_t)i * 3 + 2) * 65536,
            out_dense_b + ((size_t)i * 3 + 2) * 256, nullptr, atom3, NA, 256, 256);
        final_kernel<<<NA, 64, 0, stream>>>(atom3, out_final_w + (size_t)i * 256, out);
    };

    outblock(0, m);

    for (int i = 0; i < 4; i++) {
        // x_ji = silu(m @ ji + b)
        mfma_gemm<128, 1, 1, 0><<<dim3(E / 128, 1), 512, 0, stream>>>(
            m, ji_h + (size_t)i * 16384, ji_l + (size_t)i * 16384,
            int_ji_b + (size_t)i * 128, nullptr, A, E, 128, 128);
        // x_kj = silu(m @ kj + b)
        mfma_gemm<128, 1, 1, 0><<<dim3(E / 128, 1), 512, 0, stream>>>(
            m, kj_h + (size_t)i * 16384, kj_l + (size_t)i * 16384,
            int_kj_b + (size_t)i * 128, nullptr, B, E, 128, 128);
        // x_kj *= (rbf @ rbf1) @ rbf2
        mulg_kernel<<<E * 128 / 256, 256, 0, stream>>>(
            rbf, int_rbf1_w + (size_t)i * 48, int_rbf2_w + (size_t)i * 8 * 128, B);
        // xdown = silu(x_kj @ down)
        mfma_gemm<64, 1, 0, 0><<<dim3(E / 128, 1), 256, 0, stream>>>(
            B, dn_h + (size_t)i * 8192, dn_l + (size_t)i * 8192,
            nullptr, nullptr, D, E, 128, 64);
        // triplet segment-sum via sorted gather (no atomics; fully writes seg)
        seg_gather_kernel<<<E * 64 / 256, 256, 0, stream>>>(
            t32 + (size_t)i * T * 8, ekjs, rows, D,
            int_sbf2_w + (size_t)i * 8 * 64, seg, E);
        // hm = x_ji + silu(seg @ up)
        mfma_gemm<128, 1, 0, 1><<<dim3(E / 128, 1), 512, 0, stream>>>(
            seg, up_h + (size_t)i * 8192, up_l + (size_t)i * 8192,
            nullptr, A, C, E, 64, 128);
        // res-before
        mfma_gemm<128, 1, 1, 0><<<dim3(E / 128, 1), 512, 0, stream>>>(
            C, r1_h + ((size_t)i * 2 + 0) * 16384, r1_l + ((size_t)i * 2 + 0) * 16384,
            int_res1_b + ((size_t)i * 2 + 0) * 128, nullptr, A, E, 128, 128);
        mfma_gemm<128, 1, 1, 1><<<dim3(E / 128, 1), 512, 0, stream>>>(
            A, r1_h + ((size_t)i * 2 + 1) * 16384, r1_l + ((size_t)i * 2 + 1) * 16384,
            int_res1_b + ((size_t)i * 2 + 1) * 128, C, B, E, 128, 128);
        // m = silu(hm @ skip + b) + m
        mfma_gemm<128, 1, 1, 1><<<dim3(E / 128, 1), 512, 0, stream>>>(
            B, sk_h + (size_t)i * 16384, sk_l + (size_t)i * 16384,
            int_skip_b + (size_t)i * 128, m, m, E, 128, 128);
        // res-after x2
        for (int r = 0; r < 2; r++) {
            mfma_gemm<128, 1, 1, 0><<<dim3(E / 128, 1), 512, 0, stream>>>(
                m, r2_h + (((size_t)i * 2 + r) * 2 + 0) * 16384,
                r2_l + (((size_t)i * 2 + r) * 2 + 0) * 16384,
                int_res2_b + (((size_t)i * 2 + r) * 2 + 0) * 128, nullptr, A, E, 128, 128);
            mfma_gemm<128, 1, 1, 1><<<dim3(E / 128, 1), 512, 0, stream>>>(
                A, r2_h + (((size_t)i * 2 + r) * 2 + 1) * 16384,
                r2_l + (((size_t)i * 2 + r) * 2 + 1) * 16384,
                int_res2_b + (((size_t)i * 2 + r) * 2 + 1) * 128, m, m, E, 128, 128);
        }
        outblock(i + 1, m);
    }
}

// Round 6
// 1634.482 us; speedup vs baseline: 2.2996x; 1.1281x over previous
//
#include <hip/hip_runtime.h>
#include <cmath>

typedef __attribute__((ext_vector_type(8))) short bfrag;   // 8 bf16 = 4 VGPRs
typedef __attribute__((ext_vector_type(4))) float f32x4;

// ---------------------------------------------------------------- helpers
__device__ __forceinline__ float silu_f(float x) {
    return x / (1.0f + __expf(-x));
}
__device__ __forceinline__ unsigned short f2bf(float f) {
    unsigned u = __float_as_uint(f);
    unsigned r = (u + 0x7fff + ((u >> 16) & 1)) >> 16;
    return (unsigned short)r;
}
__device__ __forceinline__ float bf2f(unsigned short h) {
    return __uint_as_float(((unsigned)h) << 16);
}
__device__ __forceinline__ unsigned packbf2(float lo, float hi) {
    return ((unsigned)f2bf(hi) << 16) | (unsigned)f2bf(lo);
}

// LDS tile helpers: row stride 136 ushorts (272 B -> 2-way bank alias, free)
__device__ __forceinline__ void put_split4(unsigned short* Ah, unsigned short* Al,
                                           int row, int col, float4 v) {
    short4 h4, l4;
    unsigned short h;
    h = f2bf(v.x); h4.x = (short)h; l4.x = (short)f2bf(v.x - bf2f(h));
    h = f2bf(v.y); h4.y = (short)h; l4.y = (short)f2bf(v.y - bf2f(h));
    h = f2bf(v.z); h4.z = (short)h; l4.z = (short)f2bf(v.z - bf2f(h));
    h = f2bf(v.w); h4.w = (short)h; l4.w = (short)f2bf(v.w - bf2f(h));
    *(short4*)&Ah[row * 136 + col] = h4;
    *(short4*)&Al[row * 136 + col] = l4;
}

// one GEMM stage: A from LDS split planes, B (weights) streamed from global [N][K]
template <int KSTEPS, int S, int NS>
__device__ __forceinline__ void mfma_stage(
    const unsigned short* Ah, const unsigned short* Al,
    const unsigned short* __restrict__ Whi, const unsigned short* __restrict__ Wlo,
    int Kdim, int arow0, int bcol0, int r16, int kg, f32x4 (&acc)[S][NS]) {
    #pragma unroll
    for (int s = 0; s < S; s++)
        #pragma unroll
        for (int ns = 0; ns < NS; ns++) acc[s][ns] = (f32x4)0.f;
    #pragma unroll
    for (int ks = 0; ks < KSTEPS; ks++) {
        int k0 = ks * 32;
        bfrag bh[NS], bl[NS];
        #pragma unroll
        for (int ns = 0; ns < NS; ns++) {
            size_t bo = (size_t)(bcol0 + ns * 16 + r16) * Kdim + k0 + kg * 8;
            bh[ns] = *(const bfrag*)&Whi[bo];
            bl[ns] = *(const bfrag*)&Wlo[bo];
        }
        #pragma unroll
        for (int s = 0; s < S; s++) {
            int ao = (arow0 + s * 16 + r16) * 136 + k0 + kg * 8;
            bfrag ah = *(const bfrag*)&Ah[ao];
            bfrag al = *(const bfrag*)&Al[ao];
            #pragma unroll
            for (int ns = 0; ns < NS; ns++) {
                acc[s][ns] = __builtin_amdgcn_mfma_f32_16x16x32_bf16(ah, bh[ns], acc[s][ns], 0, 0, 0);
                acc[s][ns] = __builtin_amdgcn_mfma_f32_16x16x32_bf16(ah, bl[ns], acc[s][ns], 0, 0, 0);
                acc[s][ns] = __builtin_amdgcn_mfma_f32_16x16x32_bf16(al, bh[ns], acc[s][ns], 0, 0, 0);
            }
        }
    }
}

// store a 4x2-fragment array into the LDS split planes
__device__ __forceinline__ void frag_store_lds(unsigned short* Ah, unsigned short* Al,
                                               const f32x4 (&v)[4][2], int arow0, int bcol0,
                                               int r16, int kg) {
    #pragma unroll
    for (int s = 0; s < 4; s++)
        #pragma unroll
        for (int ns = 0; ns < 2; ns++)
            #pragma unroll
            for (int r = 0; r < 4; r++) {
                int row = arow0 + s * 16 + kg * 4 + r;
                int col = bcol0 + ns * 16 + r16;
                float f = v[s][ns][r];
                unsigned short h = f2bf(f);
                Ah[row * 136 + col] = h;
                Al[row * 136 + col] = f2bf(f - bf2f(h));
            }
}

// store silu(acc + bias) into LDS split planes (no extra register array)
__device__ __forceinline__ void frag_store_lds_act(unsigned short* Ah, unsigned short* Al,
                                                   const f32x4 (&a)[4][2], float bb0, float bb1,
                                                   int arow0, int bcol0, int r16, int kg) {
    float b[2] = {bb0, bb1};
    #pragma unroll
    for (int s = 0; s < 4; s++)
        #pragma unroll
        for (int ns = 0; ns < 2; ns++)
            #pragma unroll
            for (int r = 0; r < 4; r++) {
                int row = arow0 + s * 16 + kg * 4 + r;
                int col = bcol0 + ns * 16 + r16;
                float f = silu_f(a[s][ns][r] + b[ns]);
                unsigned short h = f2bf(f);
                Ah[row * 136 + col] = h;
                Al[row * 136 + col] = f2bf(f - bf2f(h));
            }
}

// ---------------------------------------------------------------- rbf (E,6)
__global__ __launch_bounds__(256) void rbf_kernel(const float* __restrict__ d,
                                                  float* __restrict__ rbf, int E) {
    int e = blockIdx.x * 256 + threadIdx.x;
    if (e >= E) return;
    float x = d[e] * 0.2f;
    float env = 0.0f;
    if (x < 1.0f) {
        float x2 = x * x;
        float x5 = x2 * x2 * x;
        env = 1.0f / x + x5 * (-28.0f + x * (48.0f - 21.0f * x));
    }
    const float SQ = 0.63245553f;
    float px = 3.14159265358979f * x;
    #pragma unroll
    for (int n = 1; n <= 6; n++) {
        rbf[e * 6 + n - 1] = SQ * env * sinf(px * (float)n);
    }
}

// ------------------------------------------- embedding precompute (1 block)
__global__ __launch_bounds__(128) void embed_pre_kernel(
    const float* __restrict__ se, const float* __restrict__ erw,
    const float* __restrict__ erb, const float* __restrict__ edw,
    float* __restrict__ HWj, float* __restrict__ HWi,
    float* __restrict__ W3, float* __restrict__ b3) {
    int c = threadIdx.x;
    for (int s = 0; s < 16; s++) {
        float aj = 0.f, ai = 0.f;
        for (int k = 0; k < 64; k++) {
            float h = se[s * 64 + k];
            aj += h * edw[k * 128 + c];
            ai += h * edw[(64 + k) * 128 + c];
        }
        HWj[s * 128 + c] = aj;
        HWi[s * 128 + c] = ai;
    }
    for (int r = 0; r < 6; r++) {
        float a = 0.f;
        for (int k = 0; k < 128; k++) a += erw[r * 128 + k] * edw[(128 + k) * 128 + c];
        W3[r * 128 + c] = a;
    }
    float a = 0.f;
    for (int k = 0; k < 128; k++) a += erb[k] * edw[(128 + k) * 128 + c];
    b3[c] = a;
}

// ---------------------------------------------------------------- m (E,128)
__global__ __launch_bounds__(256) void embed_kernel(
    const float* __restrict__ rbf, const int* __restrict__ species,
    const int* __restrict__ idx_i, const int* __restrict__ idx_j,
    const float* __restrict__ HWj, const float* __restrict__ HWi,
    const float* __restrict__ W3, const float* __restrict__ b3,
    const float* __restrict__ edb, float* __restrict__ m) {
    int gid = blockIdx.x * 256 + threadIdx.x;
    int e = gid >> 7, c = gid & 127;
    int sj = species[idx_j[e]];
    int si = species[idx_i[e]];
    float v = HWj[sj * 128 + c] + HWi[si * 128 + c] + b3[c] + edb[c];
    #pragma unroll
    for (int k = 0; k < 6; k++) v += rbf[e * 6 + k] * W3[k * 128 + c];
    m[gid] = silu_f(v);
}

// -------------------------------------- weight transpose+split (batched)
__global__ __launch_bounds__(256) void wconv_kernel(
    const float* __restrict__ W, unsigned short* __restrict__ hi,
    unsigned short* __restrict__ lo, int K, int N) {
    __shared__ float t[32][33];
    int b = blockIdx.z;
    int n0 = blockIdx.x * 32, k0 = blockIdx.y * 32;
    const float* Wb = W + (size_t)b * K * N;
    int tid = threadIdx.x;
    int r = tid >> 3, cg = tid & 7;
    float4 v = *(const float4*)&Wb[(size_t)(k0 + r) * N + n0 + cg * 4];
    t[r][cg * 4 + 0] = v.x;
    t[r][cg * 4 + 1] = v.y;
    t[r][cg * 4 + 2] = v.z;
    t[r][cg * 4 + 3] = v.w;
    __syncthreads();
    int nl = tid >> 3, kg = tid & 7;
    short4 h4, l4;
    float f0 = t[kg * 4 + 0][nl], f1 = t[kg * 4 + 1][nl];
    float f2 = t[kg * 4 + 2][nl], f3 = t[kg * 4 + 3][nl];
    unsigned short h;
    h = f2bf(f0); h4.x = (short)h; l4.x = (short)f2bf(f0 - bf2f(h));
    h = f2bf(f1); h4.y = (short)h; l4.y = (short)f2bf(f1 - bf2f(h));
    h = f2bf(f2); h4.z = (short)h; l4.z = (short)f2bf(f2 - bf2f(h));
    h = f2bf(f3); h4.w = (short)h; l4.w = (short)f2bf(f3 - bf2f(h));
    size_t o = ((size_t)b * N + n0 + nl) * K + k0 + kg * 4;
    *(short4*)&hi[o] = h4;
    *(short4*)&lo[o] = l4;
}

// ---------------------------------------------- split-bf16 MFMA dense GEMM
// (kept for the small per-atom output blocks)
template <int BN, int ACT, int BIAS, int RES>
__global__ __launch_bounds__(BN * 4) void mfma_gemm(
    const float* __restrict__ X, const unsigned short* __restrict__ Whi,
    const unsigned short* __restrict__ Wlo,
    const float* __restrict__ bias, const float* __restrict__ resid,
    float* __restrict__ Y, int M, int K, int N) {
    constexpr int T = BN * 4;
    constexpr int WC = BN / 32;
    constexpr int AP = 1024 / T;
    __shared__ unsigned short Ah[128 * 40];
    __shared__ unsigned short Al[128 * 40];
    __shared__ unsigned short Bh[BN * 40];
    __shared__ unsigned short Bl[BN * 40];

    int tid = threadIdx.x;
    int bm = blockIdx.x * 128, bn = blockIdx.y * BN;
    int wid = tid >> 6, lane = tid & 63;
    int wr = wid / WC, wc = wid % WC;
    int r16 = lane & 15, kg = lane >> 4;

    f32x4 acc[4][2];
    #pragma unroll
    for (int s = 0; s < 4; s++)
        #pragma unroll
        for (int ns = 0; ns < 2; ns++) acc[s][ns] = (f32x4)0.f;

    int brow = tid >> 2, bkg = tid & 3;

    for (int k0 = 0; k0 < K; k0 += 32) {
        float4 av[AP];
        #pragma unroll
        for (int p = 0; p < AP; p++) {
            int idx = tid + p * T;
            int row = idx >> 3, cg = idx & 7;
            av[p] = *(const float4*)&X[(size_t)(bm + row) * K + k0 + cg * 4];
        }
        float4 bh = *(const float4*)&Whi[(size_t)(bn + brow) * K + k0 + bkg * 8];
        float4 bl = *(const float4*)&Wlo[(size_t)(bn + brow) * K + k0 + bkg * 8];
        __syncthreads();
        #pragma unroll
        for (int p = 0; p < AP; p++) {
            int idx = tid + p * T;
            int row = idx >> 3, cg = idx & 7;
            float fv[4] = {av[p].x, av[p].y, av[p].z, av[p].w};
            short4 h4, l4;
            unsigned short h;
            h = f2bf(fv[0]); h4.x = (short)h; l4.x = (short)f2bf(fv[0] - bf2f(h));
            h = f2bf(fv[1]); h4.y = (short)h; l4.y = (short)f2bf(fv[1] - bf2f(h));
            h = f2bf(fv[2]); h4.z = (short)h; l4.z = (short)f2bf(fv[2] - bf2f(h));
            h = f2bf(fv[3]); h4.w = (short)h; l4.w = (short)f2bf(fv[3] - bf2f(h));
            *(short4*)&Ah[row * 40 + cg * 4] = h4;
            *(short4*)&Al[row * 40 + cg * 4] = l4;
        }
        *(float4*)&Bh[brow * 40 + bkg * 8] = bh;
        *(float4*)&Bl[brow * 40 + bkg * 8] = bl;
        __syncthreads();

        bfrag bhf[2], blf[2];
        #pragma unroll
        for (int ns = 0; ns < 2; ns++) {
            int br = wc * 32 + ns * 16 + r16;
            bhf[ns] = *(const bfrag*)&Bh[br * 40 + kg * 8];
            blf[ns] = *(const bfrag*)&Bl[br * 40 + kg * 8];
        }
        #pragma unroll
        for (int s = 0; s < 4; s++) {
            int ar = wr * 64 + s * 16 + r16;
            bfrag ah = *(const bfrag*)&Ah[ar * 40 + kg * 8];
            bfrag al = *(const bfrag*)&Al[ar * 40 + kg * 8];
            #pragma unroll
            for (int ns = 0; ns < 2; ns++) {
                acc[s][ns] = __builtin_amdgcn_mfma_f32_16x16x32_bf16(ah, bhf[ns], acc[s][ns], 0, 0, 0);
                acc[s][ns] = __builtin_amdgcn_mfma_f32_16x16x32_bf16(ah, blf[ns], acc[s][ns], 0, 0, 0);
                acc[s][ns] = __builtin_amdgcn_mfma_f32_16x16x32_bf16(al, bhf[ns], acc[s][ns], 0, 0, 0);
            }
        }
    }

    #pragma unroll
    for (int s = 0; s < 4; s++) {
        int row0 = bm + wr * 64 + s * 16 + kg * 4;
        #pragma unroll
        for (int ns = 0; ns < 2; ns++) {
            int col = bn + wc * 32 + ns * 16 + r16;
            float bv = 0.f;
            if (BIAS) bv = bias[col];
            #pragma unroll
            for (int r = 0; r < 4; r++) {
                size_t o = (size_t)(row0 + r) * N + col;
                float v = acc[s][ns][r] + bv;
                if (ACT) v = silu_f(v);
                if (RES) v += resid[o];
                Y[o] = v;
            }
        }
    }
}

// =================== fused down path: x_ji, gated x_kj, xdown =============
__global__ __launch_bounds__(512, 2) void downpath_kernel(
    const float* __restrict__ m, const float* __restrict__ rbf,
    const float* __restrict__ rbf1, const float* __restrict__ rbf2,
    const unsigned short* __restrict__ jih, const unsigned short* __restrict__ jil,
    const float* __restrict__ jib,
    const unsigned short* __restrict__ kjh, const unsigned short* __restrict__ kjl,
    const float* __restrict__ kjb,
    const unsigned short* __restrict__ dnh, const unsigned short* __restrict__ dnl,
    float* __restrict__ xji, float* __restrict__ xdown) {
    __shared__ unsigned short Ah[128 * 136];
    __shared__ unsigned short Al[128 * 136];
    __shared__ float G8s[128][8];
    int tid = threadIdx.x, bm = blockIdx.x * 128;
    int wid = tid >> 6, lane = tid & 63;
    int wr = wid >> 2, wc = wid & 3;
    int r16 = lane & 15, kg = lane >> 4;
    int arow0 = wr * 64, bcol0 = wc * 32;

    // stage m tile -> LDS split
    #pragma unroll
    for (int p = 0; p < 8; p++) {
        int idx = tid + p * 512, row = idx >> 5, cg = idx & 31;
        float4 v = *(const float4*)&m[(size_t)(bm + row) * 128 + cg * 4];
        put_split4(Ah, Al, row, cg * 4, v);
    }
    // rank-8 gate coefficients for this tile
    if (tid < 128) {
        float rv[6];
        #pragma unroll
        for (int k = 0; k < 6; k++) rv[k] = rbf[(size_t)(bm + tid) * 6 + k];
        #pragma unroll
        for (int p = 0; p < 8; p++) {
            float a = 0.f;
            #pragma unroll
            for (int k = 0; k < 6; k++) a += rv[k] * rbf1[k * 8 + p];
            G8s[tid][p] = a;
        }
    }
    __syncthreads();

    f32x4 acc[4][2];
    // ---- x_ji = silu(m @ Wji + b) -> global
    mfma_stage<4, 4, 2>(Ah, Al, jih, jil, 128, arow0, bcol0, r16, kg, acc);
    {
        float b[2] = {jib[bcol0 + r16], jib[bcol0 + 16 + r16]};
        #pragma unroll
        for (int s = 0; s < 4; s++)
            #pragma unroll
            for (int ns = 0; ns < 2; ns++)
                #pragma unroll
                for (int r = 0; r < 4; r++) {
                    int row = arow0 + s * 16 + kg * 4 + r;
                    int col = bcol0 + ns * 16 + r16;
                    xji[(size_t)(bm + row) * 128 + col] = silu_f(acc[s][ns][r] + b[ns]);
                }
    }
    // ---- x_kj = silu(m @ Wkj + b) * gate
    mfma_stage<4, 4, 2>(Ah, Al, kjh, kjl, 128, arow0, bcol0, r16, kg, acc);
    {
        float w2[2][8];
        #pragma unroll
        for (int ns = 0; ns < 2; ns++)
            #pragma unroll
            for (int p = 0; p < 8; p++) w2[ns][p] = rbf2[p * 128 + bcol0 + ns * 16 + r16];
        float b[2] = {kjb[bcol0 + r16], kjb[bcol0 + 16 + r16]};
        #pragma unroll
        for (int s = 0; s < 4; s++)
            #pragma unroll
            for (int ns = 0; ns < 2; ns++)
                #pragma unroll
                for (int r = 0; r < 4; r++) {
                    int row = arow0 + s * 16 + kg * 4 + r;
                    float g = 0.f;
                    #pragma unroll
                    for (int p = 0; p < 8; p++) g = fmaf(G8s[row][p], w2[ns][p], g);
                    acc[s][ns][r] = silu_f(acc[s][ns][r] + b[ns]) * g;
                }
    }
    __syncthreads();
    frag_store_lds(Ah, Al, acc, arow0, bcol0, r16, kg);   // overwrite m tile
    __syncthreads();
    // ---- xdown = silu(x_kj @ Wdn)  (N=64)
    {
        int wr2 = wid >> 1, wc2 = wid & 1;
        int ar2 = wr2 * 32, bc2 = wc2 * 32;
        f32x4 a2[2][2];
        mfma_stage<4, 2, 2>(Ah, Al, dnh, dnl, 128, ar2, bc2, r16, kg, a2);
        #pragma unroll
        for (int s = 0; s < 2; s++)
            #pragma unroll
            for (int ns = 0; ns < 2; ns++)
                #pragma unroll
                for (int r = 0; r < 4; r++) {
                    int row = ar2 + s * 16 + kg * 4 + r;
                    int col = bc2 + ns * 16 + r16;
                    xdown[(size_t)(bm + row) * 64 + col] = silu_f(a2[s][ns][r]);
                }
    }
}

// ============ fused update chain: up + res1 + skip + res2x2 -> m ==========
__global__ __launch_bounds__(512, 2) void chain_kernel(
    const float* __restrict__ seg, const float* __restrict__ xji, float* __restrict__ m,
    const unsigned short* __restrict__ uph, const unsigned short* __restrict__ upl,
    const unsigned short* __restrict__ r1h, const unsigned short* __restrict__ r1l,
    const float* __restrict__ r1b,
    const unsigned short* __restrict__ skh, const unsigned short* __restrict__ skl,
    const float* __restrict__ skb,
    const unsigned short* __restrict__ r2h, const unsigned short* __restrict__ r2l,
    const float* __restrict__ r2b) {
    __shared__ unsigned short Ah[128 * 136];
    __shared__ unsigned short Al[128 * 136];
    int tid = threadIdx.x, bm = blockIdx.x * 128;
    int wid = tid >> 6, lane = tid & 63;
    int wr = wid >> 2, wc = wid & 3;
    int r16 = lane & 15, kg = lane >> 4;
    int arow0 = wr * 64, bcol0 = wc * 32;

    // stage seg tile (128 x 64) -> LDS split
    #pragma unroll
    for (int p = 0; p < 4; p++) {
        int idx = tid + p * 512, row = idx >> 4, cg = idx & 15;
        float4 v = *(const float4*)&seg[(size_t)(bm + row) * 64 + cg * 4];
        put_split4(Ah, Al, row, cg * 4, v);
    }
    __syncthreads();

    f32x4 acc[4][2], res[4][2];

    // ---- hm = x_ji + silu(seg @ Wup)
    mfma_stage<2, 4, 2>(Ah, Al, uph, upl, 64, arow0, bcol0, r16, kg, acc);
    #pragma unroll
    for (int s = 0; s < 4; s++)
        #pragma unroll
        for (int ns = 0; ns < 2; ns++)
            #pragma unroll
            for (int r = 0; r < 4; r++) {
                int row = arow0 + s * 16 + kg * 4 + r;
                int col = bcol0 + ns * 16 + r16;
                res[s][ns][r] = silu_f(acc[s][ns][r]) + xji[(size_t)(bm + row) * 128 + col];
            }
    __syncthreads();
    frag_store_lds(Ah, Al, res, arow0, bcol0, r16, kg);
    __syncthreads();

    // ---- res1: t = silu(hm@W0+b0)
    mfma_stage<4, 4, 2>(Ah, Al, r1h, r1l, 128, arow0, bcol0, r16, kg, acc);
    __syncthreads();
    frag_store_lds_act(Ah, Al, acc, r1b[bcol0 + r16], r1b[bcol0 + 16 + r16],
                       arow0, bcol0, r16, kg);
    __syncthreads();
    // ---- hm += silu(t@W1+b1)
    mfma_stage<4, 4, 2>(Ah, Al, r1h + 16384, r1l + 16384, 128, arow0, bcol0, r16, kg, acc);
    {
        float b[2] = {r1b[128 + bcol0 + r16], r1b[128 + bcol0 + 16 + r16]};
        #pragma unroll
        for (int s = 0; s < 4; s++)
            #pragma unroll
            for (int ns = 0; ns < 2; ns++)
                #pragma unroll
                for (int r = 0; r < 4; r++)
                    res[s][ns][r] += silu_f(acc[s][ns][r] + b[ns]);
    }
    __syncthreads();
    frag_store_lds(Ah, Al, res, arow0, bcol0, r16, kg);
    __syncthreads();

    // ---- m' = silu(hm@Wsk+b) + m
    mfma_stage<4, 4, 2>(Ah, Al, skh, skl, 128, arow0, bcol0, r16, kg, acc);
    {
        float b[2] = {skb[bcol0 + r16], skb[bcol0 + 16 + r16]};
        #pragma unroll
        for (int s = 0; s < 4; s++)
            #pragma unroll
            for (int ns = 0; ns < 2; ns++)
                #pragma unroll
                for (int r = 0; r < 4; r++) {
                    int row = arow0 + s * 16 + kg * 4 + r;
                    int col = bcol0 + ns * 16 + r16;
                    res[s][ns][r] = silu_f(acc[s][ns][r] + b[ns]) + m[(size_t)(bm + row) * 128 + col];
                }
    }
    __syncthreads();
    frag_store_lds(Ah, Al, res, arow0, bcol0, r16, kg);
    __syncthreads();

    // ---- res2 x2
    #pragma unroll
    for (int rr = 0; rr < 2; rr++) {
        const unsigned short* wh = r2h + (size_t)rr * 2 * 16384;
        const unsigned short* wl = r2l + (size_t)rr * 2 * 16384;
        const float* bb = r2b + (size_t)rr * 2 * 128;
        mfma_stage<4, 4, 2>(Ah, Al, wh, wl, 128, arow0, bcol0, r16, kg, acc);
        __syncthreads();
        frag_store_lds_act(Ah, Al, acc, bb[bcol0 + r16], bb[bcol0 + 16 + r16],
                           arow0, bcol0, r16, kg);
        __syncthreads();
        mfma_stage<4, 4, 2>(Ah, Al, wh + 16384, wl + 16384, 128, arow0, bcol0, r16, kg, acc);
        {
            float b[2] = {bb[128 + bcol0 + r16], bb[128 + bcol0 + 16 + r16]};
            #pragma unroll
            for (int s = 0; s < 4; s++)
                #pragma unroll
                for (int ns = 0; ns < 2; ns++)
                    #pragma unroll
                    for (int r = 0; r < 4; r++)
                        res[s][ns][r] += silu_f(acc[s][ns][r] + b[ns]);
        }
        if (rr == 0) {
            __syncthreads();
            frag_store_lds(Ah, Al, res, arow0, bcol0, r16, kg);
            __syncthreads();
        }
    }
    // write final m
    #pragma unroll
    for (int s = 0; s < 4; s++)
        #pragma unroll
        for (int ns = 0; ns < 2; ns++)
            #pragma unroll
            for (int r = 0; r < 4; r++) {
                int row = arow0 + s * 16 + kg * 4 + r;
                int col = bcol0 + ns * 16 + r16;
                m[(size_t)(bm + row) * 128 + col] = res[s][ns][r];
            }
}

// ------------------------------- output block scatter: atom += seg(rbfw * m)
__global__ __launch_bounds__(256) void outseg_kernel(
    const float* __restrict__ rbf, const float* __restrict__ orw,
    const float* __restrict__ m, const int* __restrict__ idx_i,
    float* __restrict__ atom) {
    int gid = blockIdx.x * 256 + threadIdx.x;
    int e = gid >> 7, c = gid & 127;
    float s = 0.f;
    #pragma unroll
    for (int k = 0; k < 6; k++) s += rbf[e * 6 + k] * orw[k * 128 + c];
    atomicAdd(&atom[(size_t)idx_i[e] * 128 + c], s * m[gid]);
}

// ---------------------------------------------- final: out[a] += atom . wf
__global__ __launch_bounds__(64) void final_kernel(
    const float* __restrict__ atom, const float* __restrict__ wf,
    float* __restrict__ out) {
    int a = blockIdx.x, l = threadIdx.x;
    float s = 0.f;
    #pragma unroll
    for (int q = 0; q < 4; q++) s += atom[(size_t)a * 256 + q * 64 + l] * wf[q * 64 + l];
    #pragma unroll
    for (int off = 32; off; off >>= 1) s += __shfl_down(s, off, 64);
    if (l == 0) out[a] += s;
}

// ===================== triplet phase: counting sort by reduce_to_ji =======
__global__ __launch_bounds__(256) void hist_kernel(const int* __restrict__ rji,
                                                   int* __restrict__ hist) {
    int t = blockIdx.x * 256 + threadIdx.x;
    atomicAdd(&hist[rji[t]], 1);
}

__global__ __launch_bounds__(256) void scan1_kernel(const int* __restrict__ hist,
                                                    int* __restrict__ bsum) {
    __shared__ int s[256];
    int i = threadIdx.x;
    s[i] = hist[blockIdx.x * 256 + i];
    __syncthreads();
    for (int o = 128; o; o >>= 1) {
        if (i < o) s[i] += s[i + o];
        __syncthreads();
    }
    if (!i) bsum[blockIdx.x] = s[0];
}

__global__ __launch_bounds__(256) void scan2_kernel(const int* __restrict__ bsum,
                                                    int* __restrict__ boff) {
    __shared__ int s[256];
    int i = threadIdx.x;
    int own = bsum[i];
    s[i] = own;
    __syncthreads();
    for (int o = 1; o < 256; o <<= 1) {
        int v = (i >= o) ? s[i - o] : 0;
        __syncthreads();
        s[i] += v;
        __syncthreads();
    }
    boff[i] = s[i] - own;
}

__global__ __launch_bounds__(256) void scan3_kernel(const int* __restrict__ hist,
                                                    const int* __restrict__ boff,
                                                    int* __restrict__ rows,
                                                    int* __restrict__ cursor, int T) {
    __shared__ int s[256];
    int i = threadIdx.x, b = blockIdx.x;
    int h = hist[b * 256 + i];
    s[i] = h;
    __syncthreads();
    for (int o = 1; o < 256; o <<= 1) {
        int v = (i >= o) ? s[i - o] : 0;
        __syncthreads();
        s[i] += v;
        __syncthreads();
    }
    int excl = s[i] - h + boff[b];
    rows[b * 256 + i] = excl;
    cursor[b * 256 + i] = excl;
    if (b == gridDim.x - 1 && i == 255) rows[b * 256 + 256] = T;
}

__global__ __launch_bounds__(256) void scatter_kernel(
    const int* __restrict__ rji, const int* __restrict__ ekj,
    int* __restrict__ cursor, int* __restrict__ perm, int* __restrict__ ekjs) {
    int t = blockIdx.x * 256 + threadIdx.x;
    int r = rji[t];
    int pos = atomicAdd(&cursor[r], 1);
    perm[pos] = t;
    ekjs[pos] = ekj[t];
}

// ------------- sbf precompute: trig once, contract with all 4 blocks' sbf1
__global__ __launch_bounds__(256) void sbf_pre_kernel(
    const float* __restrict__ dist, const float* __restrict__ angles,
    const int* __restrict__ perm, const int* __restrict__ ekjs,
    const float* __restrict__ sbf1_all, unsigned short* __restrict__ t32, int T) {
    __shared__ float s1[1344];
    int tid = threadIdx.x;
    for (int i = tid; i < 1344; i += 256) s1[i] = sbf1_all[i];
    __syncthreads();

    int pos = blockIdx.x * 256 + tid;
    int t = perm[pos];
    int e = ekjs[pos];
    float x = fmaxf(dist[e] * 0.2f, 1e-6f);
    float env = 0.f;
    if (x < 1.0f) {
        float x2 = x * x;
        float x5 = x2 * x2 * x;
        env = 1.0f / x + x5 * (-28.0f + x * (48.0f - 21.0f * x));
    }
    float ct = cosf(angles[t]);
    float Pl[7];
    Pl[0] = 1.f;
    Pl[1] = ct;
    #pragma unroll
    for (int l = 2; l < 7; l++)
        Pl[l] = ((2.f * l - 1.f) * ct * Pl[l - 1] - (l - 1.f) * Pl[l - 2]) / (float)l;
    const float sphc[7] = {0.28209479f, 0.48860251f, 0.63078313f, 0.74635267f,
                           0.84628438f, 0.93560257f, 1.01710723f};
    const float BZ[7][6] = {
        {3.141593f, 6.283185f, 9.424778f, 12.566371f, 15.707963f, 18.849556f},
        {4.493409f, 7.725252f, 10.904122f, 14.066194f, 17.220755f, 20.371303f},
        {5.763459f, 9.095011f, 12.322941f, 15.514603f, 18.689036f, 21.853874f},
        {6.987932f, 10.417119f, 13.698023f, 16.923621f, 20.121806f, 23.304247f},
        {8.182561f, 11.704907f, 15.039665f, 18.301256f, 21.525418f, 24.727566f},
        {9.355812f, 12.966530f, 16.354710f, 19.653152f, 22.904551f, 26.126750f},
        {10.512835f, 14.207392f, 17.647975f, 20.983463f, 24.262768f, 27.507868f}};
    float sbf[42];
    #pragma unroll
    for (int l = 0; l < 7; l++) {
        float coef = env * sphc[l] * Pl[l];
        #pragma unroll
        for (int n = 0; n < 6; n++) {
            float a = BZ[l][n] * x;
            float sa, ca;
            sincosf(a, &sa, &ca);
            float inv = 1.0f / a;
            float j;
            if (l == 0) {
                j = sa * inv;
            } else {
                float jm2 = sa * inv;
                float jm1 = (sa * inv - ca) * inv;
                #pragma unroll
                for (int ll = 2; ll <= l; ll++) {
                    float jn = (2.f * ll - 1.f) * inv * jm1 - jm2;
                    jm2 = jm1;
                    jm1 = jn;
                }
                j = jm1;
            }
            sbf[l * 6 + n] = coef * j;
        }
    }
    float acc[32];
    #pragma unroll
    for (int q = 0; q < 32; q++) acc[q] = 0.f;
    #pragma unroll
    for (int k = 0; k < 42; k++) {
        float sv = sbf[k];
        #pragma unroll
        for (int b = 0; b < 4; b++)
            #pragma unroll
            for (int p = 0; p < 8; p++)
                acc[b * 8 + p] = fmaf(sv, s1[b * 336 + k * 8 + p], acc[b * 8 + p]);
    }
    #pragma unroll
    for (int b = 0; b < 4; b++) {
        uint4 u;
        u.x = packbf2(acc[b * 8 + 0], acc[b * 8 + 1]);
        u.y = packbf2(acc[b * 8 + 2], acc[b * 8 + 3]);
        u.z = packbf2(acc[b * 8 + 4], acc[b * 8 + 5]);
        u.w = packbf2(acc[b * 8 + 6], acc[b * 8 + 7]);
        *(uint4*)&t32[((size_t)b * T + pos) * 8] = u;
    }
}

// ------------- per-block gather reduce: one wave per target edge, no atomics
__global__ __launch_bounds__(256) void seg_gather_kernel(
    const unsigned short* __restrict__ t32p, const int* __restrict__ ekjs,
    const int* __restrict__ rows, const float* __restrict__ xdown,
    const float* __restrict__ sbf2, float* __restrict__ seg, int E) {
    int gid = blockIdx.x * 256 + threadIdx.x;
    int e = gid >> 6, lane = gid & 63;
    if (e >= E) return;
    float w2[8];
    #pragma unroll
    for (int p = 0; p < 8; p++) w2[p] = sbf2[p * 64 + lane];
    int p0 = rows[e], p1 = rows[e + 1];
    float acc = 0.f;
    for (int pos = p0; pos < p1; ++pos) {
        uint4 a = *(const uint4*)&t32p[(size_t)pos * 8];
        float v = __uint_as_float(a.x << 16) * w2[0] + __uint_as_float(a.x & 0xffff0000u) * w2[1]
                + __uint_as_float(a.y << 16) * w2[2] + __uint_as_float(a.y & 0xffff0000u) * w2[3]
                + __uint_as_float(a.z << 16) * w2[4] + __uint_as_float(a.z & 0xffff0000u) * w2[5]
                + __uint_as_float(a.w << 16) * w2[6] + __uint_as_float(a.w & 0xffff0000u) * w2[7];
        acc = fmaf(v, xdown[(size_t)ekjs[pos] * 64 + lane], acc);
    }
    seg[(size_t)e * 64 + lane] = acc;
}

// ---------------------------------------------------------------- launcher
extern "C" void kernel_launch(void* const* d_in, const int* in_sizes, int n_in,
                              void* d_out, int out_size, void* d_ws, size_t ws_size,
                              hipStream_t stream) {
    const float* distances   = (const float*)d_in[0];
    const float* angles      = (const float*)d_in[1];
    const float* species_emb = (const float*)d_in[2];
    const float* emb_rbf_w   = (const float*)d_in[3];
    const float* emb_rbf_b   = (const float*)d_in[4];
    const float* emb_dense_w = (const float*)d_in[5];
    const float* emb_dense_b = (const float*)d_in[6];
    const float* out_rbf_w   = (const float*)d_in[7];
    const float* out_up_w    = (const float*)d_in[8];
    const float* out_dense_w = (const float*)d_in[9];
    const float* out_dense_b = (const float*)d_in[10];
    const float* out_final_w = (const float*)d_in[11];
    const float* int_ji_w    = (const float*)d_in[12];
    const float* int_ji_b    = (const float*)d_in[13];
    const float* int_kj_w    = (const float*)d_in[14];
    const float* int_kj_b    = (const float*)d_in[15];
    const float* int_rbf1_w  = (const float*)d_in[16];
    const float* int_rbf2_w  = (const float*)d_in[17];
    const float* int_down_w  = (const float*)d_in[18];
    const float* int_sbf1_w  = (const float*)d_in[19];
    const float* int_sbf2_w  = (const float*)d_in[20];
    const float* int_up_w    = (const float*)d_in[21];
    const float* int_res1_w  = (const float*)d_in[22];
    const float* int_res1_b  = (const float*)d_in[23];
    const float* int_skip_w  = (const float*)d_in[24];
    const float* int_skip_b  = (const float*)d_in[25];
    const float* int_res2_w  = (const float*)d_in[26];
    const float* int_res2_b  = (const float*)d_in[27];
    const int*   species     = (const int*)d_in[28];
    const int*   idx_i       = (const int*)d_in[29];
    const int*   idx_j       = (const int*)d_in[30];
    const int*   reduce_ji   = (const int*)d_in[31];
    const int*   expand_kj   = (const int*)d_in[32];

    const int E = in_sizes[0];       // 65536
    const int T = in_sizes[1];       // 524288
    const int NA = in_sizes[28];     // 4096

    float* ws = (float*)d_ws;
    size_t off = 0;
    float* rbf = ws + off;   off += (size_t)E * 6;
    float* m   = ws + off;   off += (size_t)E * 128;
    float* A   = ws + off;   off += (size_t)E * 128;   // x_ji
    float* B   = ws + off;   off += (size_t)E * 128;   // seg (E x 64 used)
    float* C   = ws + off;   off += (size_t)E * 128;   // unused spare
    float* D   = ws + off;   off += (size_t)E * 64;    // xdown
    float* HWj = ws + off;   off += 16 * 128;
    float* HWi = ws + off;   off += 16 * 128;
    float* W3  = ws + off;   off += 6 * 128;
    float* b3  = ws + off;   off += 128;
    float* atom1 = ws + off; off += (size_t)NA * 128;
    float* atom2 = ws + off; off += (size_t)NA * 256;
    float* atom3 = ws + off; off += (size_t)NA * 256;
    float* seg = B;

    // bf16 weight planes (hi/lo), [N][K] layout
    unsigned short* wb = (unsigned short*)(ws + off);
    size_t wo = 0;
    unsigned short* ji_h = wb + wo;  wo += 4 * 16384;
    unsigned short* ji_l = wb + wo;  wo += 4 * 16384;
    unsigned short* kj_h = wb + wo;  wo += 4 * 16384;
    unsigned short* kj_l = wb + wo;  wo += 4 * 16384;
    unsigned short* dn_h = wb + wo;  wo += 4 * 8192;
    unsigned short* dn_l = wb + wo;  wo += 4 * 8192;
    unsigned short* up_h = wb + wo;  wo += 4 * 8192;
    unsigned short* up_l = wb + wo;  wo += 4 * 8192;
    unsigned short* r1_h = wb + wo;  wo += 8 * 16384;
    unsigned short* r1_l = wb + wo;  wo += 8 * 16384;
    unsigned short* sk_h = wb + wo;  wo += 4 * 16384;
    unsigned short* sk_l = wb + wo;  wo += 4 * 16384;
    unsigned short* r2_h = wb + wo;  wo += 16 * 16384;
    unsigned short* r2_l = wb + wo;  wo += 16 * 16384;
    unsigned short* ou_h = wb + wo;  wo += 5 * 32768;
    unsigned short* ou_l = wb + wo;  wo += 5 * 32768;
    unsigned short* od_h = wb + wo;  wo += 15 * 65536;
    unsigned short* od_l = wb + wo;  wo += 15 * 65536;
    // triplet-sort structures
    unsigned short* t32 = wb + wo;   wo += (size_t)4 * T * 8;
    int* ip    = (int*)(wb + wo);
    size_t io  = 0;
    int* hist   = ip + io;  io += E;
    int* rows   = ip + io;  io += E + 64;
    int* cursor = ip + io;  io += E;
    int* bsum   = ip + io;  io += 256;
    int* boff   = ip + io;  io += 256;
    int* perm   = ip + io;  io += T;
    int* ekjs   = ip + io;  io += T;

    float* out = (float*)d_out;
    hipMemsetAsync(out, 0, (size_t)out_size * sizeof(float), stream);

    // ---- triplet counting sort + basis precompute (once per launch)
    hipMemsetAsync(hist, 0, (size_t)E * sizeof(int), stream);
    hist_kernel<<<T / 256, 256, 0, stream>>>(reduce_ji, hist);
    scan1_kernel<<<E / 256, 256, 0, stream>>>(hist, bsum);
    scan2_kernel<<<1, 256, 0, stream>>>(bsum, boff);
    scan3_kernel<<<E / 256, 256, 0, stream>>>(hist, boff, rows, cursor, T);
    scatter_kernel<<<T / 256, 256, 0, stream>>>(reduce_ji, expand_kj, cursor, perm, ekjs);
    sbf_pre_kernel<<<T / 256, 256, 0, stream>>>(distances, angles, perm, ekjs,
                                                int_sbf1_w, t32, T);

    // weight conversion (once per launch)
    wconv_kernel<<<dim3(4, 4, 4), 256, 0, stream>>>(int_ji_w, ji_h, ji_l, 128, 128);
    wconv_kernel<<<dim3(4, 4, 4), 256, 0, stream>>>(int_kj_w, kj_h, kj_l, 128, 128);
    wconv_kernel<<<dim3(2, 4, 4), 256, 0, stream>>>(int_down_w, dn_h, dn_l, 128, 64);
    wconv_kernel<<<dim3(4, 2, 4), 256, 0, stream>>>(int_up_w, up_h, up_l, 64, 128);
    wconv_kernel<<<dim3(4, 4, 8), 256, 0, stream>>>(int_res1_w, r1_h, r1_l, 128, 128);
    wconv_kernel<<<dim3(4, 4, 4), 256, 0, stream>>>(int_skip_w, sk_h, sk_l, 128, 128);
    wconv_kernel<<<dim3(4, 4, 16), 256, 0, stream>>>(int_res2_w, r2_h, r2_l, 128, 128);
    wconv_kernel<<<dim3(8, 4, 5), 256, 0, stream>>>(out_up_w, ou_h, ou_l, 128, 256);
    wconv_kernel<<<dim3(8, 8, 15), 256, 0, stream>>>(out_dense_w, od_h, od_l, 256, 256);

    rbf_kernel<<<E / 256, 256, 0, stream>>>(distances, rbf, E);
    embed_pre_kernel<<<1, 128, 0, stream>>>(species_emb, emb_rbf_w, emb_rbf_b,
                                            emb_dense_w, HWj, HWi, W3, b3);
    embed_kernel<<<E * 128 / 256, 256, 0, stream>>>(rbf, species, idx_i, idx_j,
                                                    HWj, HWi, W3, b3, emb_dense_b, m);

    auto outblock = [&](int i, const float* msg) {
        hipMemsetAsync(atom1, 0, (size_t)NA * 128 * sizeof(float), stream);
        outseg_kernel<<<E * 128 / 256, 256, 0, stream>>>(
            rbf, out_rbf_w + (size_t)i * 6 * 128, msg, idx_i, atom1);
        mfma_gemm<128, 0, 0, 0><<<dim3(NA / 128, 2), 512, 0, stream>>>(
            atom1, ou_h + (size_t)i * 32768, ou_l + (size_t)i * 32768,
            nullptr, nullptr, atom2, NA, 128, 256);
        mfma_gemm<128, 1, 1, 0><<<dim3(NA / 128, 2), 512, 0, stream>>>(
            atom2, od_h + ((size_t)i * 3 + 0) * 65536, od_l + ((size_t)i * 3 + 0) * 65536,
            out_dense_b + ((size_t)i * 3 + 0) * 256, nullptr, atom3, NA, 256, 256);
        mfma_gemm<128, 1, 1, 0><<<dim3(NA / 128, 2), 512, 0, stream>>>(
            atom3, od_h + ((size_t)i * 3 + 1) * 65536, od_l + ((size_t)i * 3 + 1) * 65536,
            out_dense_b + ((size_t)i * 3 + 1) * 256, nullptr, atom2, NA, 256, 256);
        mfma_gemm<128, 1, 1, 0><<<dim3(NA / 128, 2), 512, 0, stream>>>(
            atom2, od_h + ((size_t)i * 3 + 2) * 65536, od_l + ((size_t)i * 3 + 2) * 65536,
            out_dense_b + ((size_t)i * 3 + 2) * 256, nullptr, atom3, NA, 256, 256);
        final_kernel<<<NA, 64, 0, stream>>>(atom3, out_final_w + (size_t)i * 256, out);
    };

    outblock(0, m);

    for (int i = 0; i < 4; i++) {
        // fused: x_ji, gated x_kj, xdown
        downpath_kernel<<<E / 128, 512, 0, stream>>>(
            m, rbf, int_rbf1_w + (size_t)i * 48, int_rbf2_w + (size_t)i * 1024,
            ji_h + (size_t)i * 16384, ji_l + (size_t)i * 16384, int_ji_b + (size_t)i * 128,
            kj_h + (size_t)i * 16384, kj_l + (size_t)i * 16384, int_kj_b + (size_t)i * 128,
            dn_h + (size_t)i * 8192, dn_l + (size_t)i * 8192,
            A, D);
        // triplet segment-sum via sorted gather
        seg_gather_kernel<<<E * 64 / 256, 256, 0, stream>>>(
            t32 + (size_t)i * T * 8, ekjs, rows, D,
            int_sbf2_w + (size_t)i * 8 * 64, seg, E);
        // fused: up + res1 + skip + res2x2 -> m
        chain_kernel<<<E / 128, 512, 0, stream>>>(
            seg, A, m,
            up_h + (size_t)i * 8192, up_l + (size_t)i * 8192,
            r1_h + (size_t)i * 32768, r1_l + (size_t)i * 32768, int_res1_b + (size_t)i * 256,
            sk_h + (size_t)i * 16384, sk_l + (size_t)i * 16384, int_skip_b + (size_t)i * 128,
            r2_h + (size_t)i * 65536, r2_l + (size_t)i * 65536, int_res2_b + (size_t)i * 512);
        outblock(i + 1, m);
    }
}